// Round 9
// baseline (12058.443 us; speedup 1.0000x reference)
//
#include <hip/hip_runtime.h>

// Round 9: R7 base + counted-vmcnt prefetch of the encT stream under P1
// (T4 pattern), wave-local softmax in P2 (no syncthreads), FMA from registers.
// 256 blocks x 512 threads, 3 barriers/step, flat release barrier (R7's).

typedef unsigned short u16;
typedef unsigned int u32;
typedef __attribute__((ext_vector_type(8))) short short8;
typedef __attribute__((ext_vector_type(4))) float f32x4;
typedef __attribute__((ext_vector_type(4))) u32 u32x4;
typedef __attribute__((ext_vector_type(2))) u32 u32x2;

#define MFMA16(a, b, c) __builtin_amdgcn_mfma_f32_16x16x32_bf16((a), (b), (c), 0, 0, 0)

// ---- ws layout ----
#define U_ENC 0u           // encT bf16 [128 b][256 t][512 c]  (32MB)
#define U_WHH 16777216u
#define U_WIH 17563648u
#define U_WAW 18350080u
#define U_WOW 18546688u
#define U_WCE 18677760u
#define U_WXT 18808832u
#define U_HB  18874368u
#define U_EB  18939904u
#define U_XB  18972672u
#define U_PB  19038208u
#define F_LGB 9535488u
#define F_EMB 9568256u
#define F_EPB 9601024u
#define F_GHB 9666560u
#define F_SRB 9863168u
#define F_MFB 9895936u
#define F_NEB 9896064u
#define F_NSB 9896192u
#define F_BAR 9896448u
#define BAR_N 198147u

__device__ __forceinline__ float bf2f(u16 u) { return __uint_as_float(((u32)u) << 16); }
__device__ __forceinline__ u16 f2bf(float f) {
  u32 u = __float_as_uint(f);
  return (u16)((u + 0x7FFFu + ((u >> 16) & 1u)) >> 16);
}
__device__ __forceinline__ u32 pk2(float a, float b) {
  return (u32)f2bf(a) | ((u32)f2bf(b) << 16);
}

// ---- coherent (sc0 sc1) load/store helpers (waiting variants) ----
__device__ __forceinline__ float ldcg_f(const float* p) {
  float r;
  asm volatile("global_load_dword %0, %1, off sc0 sc1\n\ts_waitcnt vmcnt(0)"
               : "=v"(r) : "v"(p));
  return r;
}
__device__ __forceinline__ f32x4 ldcg_f4(const float* p) {
  f32x4 r;
  asm volatile("global_load_dwordx4 %0, %1, off sc0 sc1\n\ts_waitcnt vmcnt(0)"
               : "=v"(r) : "v"(p));
  return r;
}
__device__ __forceinline__ u32x2 ldcg_b8(const u16* p) {
  u32x2 r;
  asm volatile("global_load_dwordx2 %0, %1, off sc0 sc1\n\ts_waitcnt vmcnt(0)"
               : "=v"(r) : "v"(p));
  return r;
}
__device__ __forceinline__ void ldcg_f4x3(f32x4& a, f32x4& b, f32x4& c,
                                          const float* p0, const float* p1,
                                          const float* p2) {
  asm volatile(
      "global_load_dwordx4 %0, %3, off sc0 sc1\n\t"
      "global_load_dwordx4 %1, %4, off sc0 sc1\n\t"
      "global_load_dwordx4 %2, %5, off sc0 sc1\n\t"
      "s_waitcnt vmcnt(0)"
      : "=&v"(a), "=&v"(b), "=&v"(c)
      : "v"(p0), "v"(p1), "v"(p2));
}
__device__ __forceinline__ void ldcg8(u32x4 d[8], const u16* p) {
  asm volatile(
      "global_load_dwordx4 %0, %8, off sc0 sc1\n\t"
      "global_load_dwordx4 %1, %8, off offset:64 sc0 sc1\n\t"
      "global_load_dwordx4 %2, %8, off offset:128 sc0 sc1\n\t"
      "global_load_dwordx4 %3, %8, off offset:192 sc0 sc1\n\t"
      "global_load_dwordx4 %4, %8, off offset:256 sc0 sc1\n\t"
      "global_load_dwordx4 %5, %8, off offset:320 sc0 sc1\n\t"
      "global_load_dwordx4 %6, %8, off offset:384 sc0 sc1\n\t"
      "global_load_dwordx4 %7, %8, off offset:448 sc0 sc1\n\t"
      "s_waitcnt vmcnt(0)"
      : "=&v"(d[0]), "=&v"(d[1]), "=&v"(d[2]), "=&v"(d[3]),
        "=&v"(d[4]), "=&v"(d[5]), "=&v"(d[6]), "=&v"(d[7])
      : "v"(p));
}
__device__ __forceinline__ void ldcg16(u32x4 d[16], const u16* p) {
  asm volatile(
      "global_load_dwordx4 %0, %16, off sc0 sc1\n\t"
      "global_load_dwordx4 %1, %16, off offset:64 sc0 sc1\n\t"
      "global_load_dwordx4 %2, %16, off offset:128 sc0 sc1\n\t"
      "global_load_dwordx4 %3, %16, off offset:192 sc0 sc1\n\t"
      "global_load_dwordx4 %4, %16, off offset:256 sc0 sc1\n\t"
      "global_load_dwordx4 %5, %16, off offset:320 sc0 sc1\n\t"
      "global_load_dwordx4 %6, %16, off offset:384 sc0 sc1\n\t"
      "global_load_dwordx4 %7, %16, off offset:448 sc0 sc1\n\t"
      "global_load_dwordx4 %8, %16, off offset:512 sc0 sc1\n\t"
      "global_load_dwordx4 %9, %16, off offset:576 sc0 sc1\n\t"
      "global_load_dwordx4 %10, %16, off offset:640 sc0 sc1\n\t"
      "global_load_dwordx4 %11, %16, off offset:704 sc0 sc1\n\t"
      "global_load_dwordx4 %12, %16, off offset:768 sc0 sc1\n\t"
      "global_load_dwordx4 %13, %16, off offset:832 sc0 sc1\n\t"
      "global_load_dwordx4 %14, %16, off offset:896 sc0 sc1\n\t"
      "global_load_dwordx4 %15, %16, off offset:960 sc0 sc1\n\t"
      "s_waitcnt vmcnt(0)"
      : "=&v"(d[0]), "=&v"(d[1]), "=&v"(d[2]), "=&v"(d[3]),
        "=&v"(d[4]), "=&v"(d[5]), "=&v"(d[6]), "=&v"(d[7]),
        "=&v"(d[8]), "=&v"(d[9]), "=&v"(d[10]), "=&v"(d[11]),
        "=&v"(d[12]), "=&v"(d[13]), "=&v"(d[14]), "=&v"(d[15])
      : "v"(p));
}
// ---- no-wait variants (counted-vmcnt pattern) ----
__device__ __forceinline__ f32x4 ldcg_f4_nw(const float* p) {
  f32x4 r;
  asm volatile("global_load_dwordx4 %0, %1, off sc0 sc1" : "=v"(r) : "v"(p));
  return r;
}
__device__ __forceinline__ void ldcg8_nw(u32x4 d[8], const u16* p) {
  asm volatile(
      "global_load_dwordx4 %0, %8, off sc0 sc1\n\t"
      "global_load_dwordx4 %1, %8, off offset:64 sc0 sc1\n\t"
      "global_load_dwordx4 %2, %8, off offset:128 sc0 sc1\n\t"
      "global_load_dwordx4 %3, %8, off offset:192 sc0 sc1\n\t"
      "global_load_dwordx4 %4, %8, off offset:256 sc0 sc1\n\t"
      "global_load_dwordx4 %5, %8, off offset:320 sc0 sc1\n\t"
      "global_load_dwordx4 %6, %8, off offset:384 sc0 sc1\n\t"
      "global_load_dwordx4 %7, %8, off offset:448 sc0 sc1"
      : "=&v"(d[0]), "=&v"(d[1]), "=&v"(d[2]), "=&v"(d[3]),
        "=&v"(d[4]), "=&v"(d[5]), "=&v"(d[6]), "=&v"(d[7])
      : "v"(p));
}
__device__ __forceinline__ void ldcg16_nw(u32x4 d[16], const u16* p) {
  asm volatile(
      "global_load_dwordx4 %0, %16, off sc0 sc1\n\t"
      "global_load_dwordx4 %1, %16, off offset:64 sc0 sc1\n\t"
      "global_load_dwordx4 %2, %16, off offset:128 sc0 sc1\n\t"
      "global_load_dwordx4 %3, %16, off offset:192 sc0 sc1\n\t"
      "global_load_dwordx4 %4, %16, off offset:256 sc0 sc1\n\t"
      "global_load_dwordx4 %5, %16, off offset:320 sc0 sc1\n\t"
      "global_load_dwordx4 %6, %16, off offset:384 sc0 sc1\n\t"
      "global_load_dwordx4 %7, %16, off offset:448 sc0 sc1\n\t"
      "global_load_dwordx4 %8, %16, off offset:512 sc0 sc1\n\t"
      "global_load_dwordx4 %9, %16, off offset:576 sc0 sc1\n\t"
      "global_load_dwordx4 %10, %16, off offset:640 sc0 sc1\n\t"
      "global_load_dwordx4 %11, %16, off offset:704 sc0 sc1\n\t"
      "global_load_dwordx4 %12, %16, off offset:768 sc0 sc1\n\t"
      "global_load_dwordx4 %13, %16, off offset:832 sc0 sc1\n\t"
      "global_load_dwordx4 %14, %16, off offset:896 sc0 sc1\n\t"
      "global_load_dwordx4 %15, %16, off offset:960 sc0 sc1"
      : "=&v"(d[0]), "=&v"(d[1]), "=&v"(d[2]), "=&v"(d[3]),
        "=&v"(d[4]), "=&v"(d[5]), "=&v"(d[6]), "=&v"(d[7]),
        "=&v"(d[8]), "=&v"(d[9]), "=&v"(d[10]), "=&v"(d[11]),
        "=&v"(d[12]), "=&v"(d[13]), "=&v"(d[14]), "=&v"(d[15])
      : "v"(p));
}
// 4 nontemporal dwordx2 loads, t-stride 1024B, no wait
__device__ __forceinline__ void ldnt4(u32x2 d[4], const u16* p) {
  asm volatile(
      "global_load_dwordx2 %0, %4, off nt\n\t"
      "global_load_dwordx2 %1, %4, off offset:1024 nt\n\t"
      "global_load_dwordx2 %2, %4, off offset:2048 nt\n\t"
      "global_load_dwordx2 %3, %4, off offset:3072 nt"
      : "=&v"(d[0]), "=&v"(d[1]), "=&v"(d[2]), "=&v"(d[3])
      : "v"(p));
}
#define VMW32 do { asm volatile("s_waitcnt vmcnt(32)"); __builtin_amdgcn_sched_barrier(0); } while (0)
#define VMW0  do { asm volatile("s_waitcnt vmcnt(0)");  __builtin_amdgcn_sched_barrier(0); } while (0)

__device__ __forceinline__ void stcg_f(float* p, float v) {
  asm volatile("global_store_dword %0, %1, off sc0 sc1" ::"v"(p), "v"(v) : "memory");
}
__device__ __forceinline__ void stcg_f4(float* p, f32x4 v) {
  asm volatile("global_store_dwordx4 %0, %1, off sc0 sc1" ::"v"(p), "v"(v) : "memory");
}
__device__ __forceinline__ void stcg_b8(u16* p, u32x2 v) {
  asm volatile("global_store_dwordx2 %0, %1, off sc0 sc1" ::"v"(p), "v"(v) : "memory");
}

// prefetch this wave's P2 encT slice: t = w*32+j, c = chalf*256 + lane*4 .. +3
__device__ __forceinline__ void prefetch_enc(u32x2 pf[32], const u16* ENC,
                                             int blk, int w, int lane) {
  const u16* pfb = ENC + (size_t)(blk & 127) * 131072u + (size_t)(w * 32) * 512u +
                   ((blk >> 7) * 256) + lane * 4;
#pragma unroll
  for (int j8 = 0; j8 < 8; ++j8) ldnt4(pf + j8 * 4, pfb + j8 * 2048);
}

// ---- flat two-level barrier (R7's measured-good variant) ----
__device__ __forceinline__ void gbar2(u32* bar, u32 gen, int grp) {
  __syncthreads();
  if (threadIdx.x == 0) {
    u32* l1 = bar + ((size_t)gen * 16u + (u32)grp) * 16u;
    u32* rel = bar + 197376u + gen;
    const u32 old = __hip_atomic_fetch_add(l1, 1u, __ATOMIC_RELAXED,
                                           __HIP_MEMORY_SCOPE_AGENT);
    if (old == 15u)
      __hip_atomic_fetch_add(rel, 1u, __ATOMIC_RELAXED, __HIP_MEMORY_SCOPE_AGENT);
    while (__hip_atomic_load(rel, __ATOMIC_RELAXED, __HIP_MEMORY_SCOPE_AGENT) < 16u) {}
  }
  __syncthreads();
}

// ---------------- weight convert ----------------
__global__ void __launch_bounds__(256) kPrep(const float* __restrict__ wih,
                                             const float* __restrict__ whh,
                                             const float* __restrict__ aW,
                                             const float* __restrict__ oW,
                                             const float* __restrict__ cW,
                                             const float* __restrict__ ct,
                                             float* __restrict__ ws) {
  u16* W = (u16*)ws;
  const u32 i = blockIdx.x * 256 + threadIdx.x;
  if (i < 786432u) {
    W[U_WHH + i] = f2bf(whh[i]);
  } else if (i < 1572864u) {
    const u32 j = i - 786432u;
    W[U_WIH + j] = f2bf(wih[j]);
  } else if (i < 1769472u) {
    const u32 j = i - 1572864u;
    W[U_WAW + j] = f2bf(aW[j]);
  } else if (i < 1900544u) {
    const u32 j = i - 1769472u;
    W[U_WOW + j] = f2bf(oW[j]);
  } else if (i < 2031616u) {
    const u32 j = i - 1900544u;
    W[U_WCE + j] = f2bf(cW[(size_t)(j >> 8) * 1280 + (j & 255u)]);
  } else {
    const u32 j = i - 2031616u;
    const u32 kn = j >> 8, k = j & 255u;
    W[U_WXT + j] = f2bf(__expf(ct[k * 256u + kn]));
  }
}

// ---------------- init ----------------
__global__ void __launch_bounds__(256) kInit(const int* __restrict__ dec,
                                             const int* __restrict__ tags,
                                             const float* __restrict__ emb,
                                             const float* __restrict__ cs,
                                             const float* __restrict__ ce,
                                             const float* __restrict__ ct,
                                             float* __restrict__ ws) {
  const u32 idx = blockIdx.x * 256 + threadIdx.x;
  u16* ENC = (u16*)ws;
  u16* HB = ENC + U_HB;
  u16* EB = ENC + U_EB;
  if (idx < 32768u) {
    ((u32*)HB)[idx] = 0u;
    const int b = idx >> 8, j = idx & 255;
    EB[idx] = f2bf(emb[(size_t)dec[b] * 256 + j]);
  }
  if (idx < 128u) {
    int prev = tags[idx];
    float a = cs[prev];
    for (int t = 1; t < 256; ++t) {
      const int cur = tags[t * 128 + idx];
      a += ct[prev * 256 + cur];
      prev = cur;
    }
    ws[F_NSB + idx] = a + ce[prev];
    ws[F_NEB + idx] = 0.f;
  }
  u32* bar = (u32*)(ws + F_BAR);
  if (idx < 49537u) {
#pragma unroll
    for (int j = 0; j < 4; ++j) {
      const u32 k = idx * 4u + (u32)j;
      if (k < BAR_N) bar[k] = 0u;
    }
  }
}

// ---------------- encT precompute ----------------
__global__ void __launch_bounds__(256) kEncW(const float* __restrict__ enc,
                                             const float* __restrict__ cW,
                                             u16* __restrict__ encT) {
  __shared__ float wL[64 * 64];
  const int t = blockIdx.x >> 3, cblk = blockIdx.x & 7;
  const int tid = threadIdx.x;
  const int bg = tid & 31;
  const int cg = tid >> 5;
  float acc[4][8];
#pragma unroll
  for (int i = 0; i < 4; ++i)
#pragma unroll
    for (int c = 0; c < 8; ++c) acc[i][c] = 0.f;
  const float* encB = enc + (size_t)t * (128 * 1024);
  for (int jt = 0; jt < 16; ++jt) {
    const int j0 = jt * 64;
    __syncthreads();
    for (int i = tid; i < 4096; i += 256) {
      const int cc = i >> 6, jj = i & 63;
      wL[cc * 64 + jj] = cW[(size_t)(cblk * 64 + cc) * 1280 + 256 + j0 + jj];
    }
    __syncthreads();
    for (int jj = 0; jj < 64; ++jj) {
      const float e0 = encB[(bg * 4 + 0) * 1024 + j0 + jj];
      const float e1 = encB[(bg * 4 + 1) * 1024 + j0 + jj];
      const float e2 = encB[(bg * 4 + 2) * 1024 + j0 + jj];
      const float e3 = encB[(bg * 4 + 3) * 1024 + j0 + jj];
#pragma unroll
      for (int c = 0; c < 8; ++c) {
        const float wv = wL[(cg * 8 + c) * 64 + jj];
        acc[0][c] = fmaf(e0, wv, acc[0][c]);
        acc[1][c] = fmaf(e1, wv, acc[1][c]);
        acc[2][c] = fmaf(e2, wv, acc[2][c]);
        acc[3][c] = fmaf(e3, wv, acc[3][c]);
      }
    }
  }
#pragma unroll
  for (int i = 0; i < 4; ++i)
    for (int c = 0; c < 8; ++c) {
      const int b = bg * 4 + i, cc = cblk * 64 + cg * 8 + c;
      encT[(size_t)b * 131072u + (size_t)t * 512u + cc] = f2bf(acc[i][c]);
    }
}

struct P9 {
  const int* dec; const int* tags; const float* emb;
  const float* ab; const float* cb; const float* bih; const float* bhh;
  const float* ob; const float* cs;
  float* ws;
};

// ---------------- main cooperative kernel ----------------
__global__ void __launch_bounds__(512, 2) maink(P9 p) {
  float* const ws = p.ws;
  u16* const ENC = (u16*)ws;
  const u16* const WHH16 = ENC + U_WHH;
  const u16* const WIH16 = ENC + U_WIH;
  const u16* const WAW16 = ENC + U_WAW;
  const u16* const WOW16 = ENC + U_WOW;
  const u16* const WCE16 = ENC + U_WCE;
  const u16* const WXT16 = ENC + U_WXT;
  u16* const HB = ENC + U_HB;
  u16* const EB = ENC + U_EB;
  u16* const XB = ENC + U_XB;
  u16* const PBu = ENC + U_PB;
  float* const LGB = ws + F_LGB;
  float* const EMB = ws + F_EMB;
  float* const EPB = ws + F_EPB;
  float* const GHB = ws + F_GHB;
  float* const SRB = ws + F_SRB;
  float* const MFB = ws + F_MFB;
  float* const NEB = ws + F_NEB;
  u32* const bar = (u32*)(ws + F_BAR);

  __shared__ float PL[8 * 260];
  __shared__ float pr3[3][256];

  const int tid = threadIdx.x;
  const int w = tid >> 6, lane = tid & 63;
  const int bq = lane & 15, kg = lane >> 4;
  const int blk = blockIdx.x;
  const int grp = blk >> 4;
  u32 gen = 0;

  for (int s = 0; s <= 256; ++s) {
    u32x2 pf[32];  // this wave's P2 encT slice (prefetched during P1)

    // ================= P1 =================
    if (w < 3) {
      if (s < 256) {  // gh: t = w*256+blk
        const int t = w * 256 + blk;
        const int r0 = (t >> 3) * 16, b0 = (t & 7) * 16;
        f32x4 acc;
        const float4 bs = *(const float4*)(p.bhh + r0 + kg * 4);
        acc[0] = bs.x; acc[1] = bs.y; acc[2] = bs.z; acc[3] = bs.w;
        u32x4 Bf[16];
        ldcg16_nw(Bf, HB + (size_t)(b0 + bq) * 512 + kg * 8);
        prefetch_enc(pf, ENC, blk, w, lane);
        VMW32;  // own 16 loads complete; stream stays in flight
        const u16* Ar = WHH16 + (size_t)(r0 + bq) * 512 + kg * 8;
#pragma unroll
        for (int kt = 0; kt < 16; ++kt)
          acc = MFMA16(*(const short8*)(Ar + kt * 32),
                       __builtin_bit_cast(short8, Bf[kt]), acc);
        stcg_f4(GHB + (size_t)(b0 + bq) * 1536 + r0 + kg * 4, acc);
      }
    } else if (w == 3) {
      if (blk < 128) {
        if (s < 256) {  // attn logits, K=768 (heavy: prefetch AFTER task for reg peak)
          const int r0 = (blk >> 3) * 16, b0 = (blk & 7) * 16;
          f32x4 acc;
          const float4 bs = *(const float4*)(p.ab + r0 + kg * 4);
          acc[0] = bs.x; acc[1] = bs.y; acc[2] = bs.z; acc[3] = bs.w;
          u32x4 Ef[8], Hf[16];
          ldcg8_nw(Ef, EB + (size_t)(b0 + bq) * 256 + kg * 8);
          ldcg16(Hf, HB + (size_t)(b0 + bq) * 512 + kg * 8);  // waits all 24
          const u16* Ar = WAW16 + (size_t)(r0 + bq) * 768 + kg * 8;
#pragma unroll
          for (int kt = 0; kt < 8; ++kt)
            acc = MFMA16(*(const short8*)(Ar + kt * 32),
                         __builtin_bit_cast(short8, Ef[kt]), acc);
#pragma unroll
          for (int kt = 0; kt < 16; ++kt)
            acc = MFMA16(*(const short8*)(Ar + 256 + kt * 32),
                         __builtin_bit_cast(short8, Hf[kt]), acc);
          stcg_f4(LGB + (size_t)(b0 + bq) * 256 + r0 + kg * 4, acc);
          prefetch_enc(pf, ENC, blk, w, lane);
        }
      } else {
        if (s >= 1) {  // em_{s-1}
          const int t2 = blk - 128;
          const int r0 = (t2 >> 3) * 16, b0 = (t2 & 7) * 16;
          f32x4 acc;
          const float4 bs = *(const float4*)(p.ob + r0 + kg * 4);
          acc[0] = bs.x; acc[1] = bs.y; acc[2] = bs.z; acc[3] = bs.w;
          u32x4 Hf[16];
          ldcg16_nw(Hf, HB + (size_t)(b0 + bq) * 512 + kg * 8);
          if (s < 256) { prefetch_enc(pf, ENC, blk, w, lane); VMW32; } else { VMW0; }
          const u16* Ar = WOW16 + (size_t)(r0 + bq) * 512 + kg * 8;
#pragma unroll
          for (int kt = 0; kt < 16; ++kt)
            acc = MFMA16(*(const short8*)(Ar + kt * 32),
                         __builtin_bit_cast(short8, Hf[kt]), acc);
          stcg_f4(EMB + (size_t)(b0 + bq) * 256 + r0 + kg * 4, acc);
        } else {
          prefetch_enc(pf, ENC, blk, w, lane);  // s==0
        }
      }
    } else if (w == 4) {
      if (s < 256) {  // ep
        const int r0 = (blk >> 3) * 16, b0 = (blk & 7) * 16;
        f32x4 acc;
        const float4 bs = *(const float4*)(p.cb + r0 + kg * 4);
        acc[0] = bs.x; acc[1] = bs.y; acc[2] = bs.z; acc[3] = bs.w;
        u32x4 Ef[8];
        ldcg8_nw(Ef, EB + (size_t)(b0 + bq) * 256 + kg * 8);
        prefetch_enc(pf, ENC, blk, w, lane);
        VMW32;
        const u16* Ar = WCE16 + (size_t)(r0 + bq) * 256 + kg * 8;
#pragma unroll
        for (int kt = 0; kt < 8; ++kt)
          acc = MFMA16(*(const short8*)(Ar + kt * 32),
                       __builtin_bit_cast(short8, Ef[kt]), acc);
        stcg_f4(EPB + (size_t)(b0 + bq) * 512 + r0 + kg * 4, acc);
      }
    } else if (w == 5) {
      if (blk < 128 && s >= 2) {  // CRF-A
        const int b = blk;
        const f32x4 sv = ldcg_f4_nw(SRB + (size_t)b * 256 + lane * 4);
        if (s < 256) { prefetch_enc(pf, ENC, blk, w, lane); VMW32; } else { VMW0; }
        float mx = fmaxf(fmaxf(sv[0], sv[1]), fmaxf(sv[2], sv[3]));
#pragma unroll
        for (int o = 32; o; o >>= 1) mx = fmaxf(mx, __shfl_xor(mx, o));
        u32x2 pv;
        pv[0] = pk2(__expf(sv[0] - mx), __expf(sv[1] - mx));
        pv[1] = pk2(__expf(sv[2] - mx), __expf(sv[3] - mx));
        stcg_b8(PBu + (size_t)b * 256 + lane * 4, pv);
        if (lane == 0) stcg_f(MFB + b, mx);
      } else if (s < 256) {
        prefetch_enc(pf, ENC, blk, w, lane);
      }
    } else {  // w == 6, 7: idle in P1 -> prefetch immediately
      if (s < 256) prefetch_enc(pf, ENC, blk, w, lane);
    }
    gbar2(bar, gen++, grp);

    // ================= P2: wave softmax + ctx from prefetched regs =================
    {
      const int b = blk & 127, chalf = blk >> 7;
      if (s < 256) {
        const f32x4 lg = ldcg_f4(LGB + (size_t)b * 256 + lane * 4);  // drains stream too
        float m = fmaxf(fmaxf(lg[0], lg[1]), fmaxf(lg[2], lg[3]));
#pragma unroll
        for (int o = 32; o; o >>= 1) m = fmaxf(m, __shfl_xor(m, o));
        f32x4 pr;
        float sm = 0.f;
#pragma unroll
        for (int i = 0; i < 4; ++i) { pr[i] = __expf(lg[i] - m); sm += pr[i]; }
#pragma unroll
        for (int o = 32; o; o >>= 1) sm += __shfl_xor(sm, o);
        const float inv = 1.f / sm;
        float prr[32];
#pragma unroll
        for (int j = 0; j < 32; ++j)
          prr[j] = __shfl(pr[j & 3], w * 8 + (j >> 2), 64);
        VMW0;  // pf registers valid beyond this point (rule-18 fence)
        float a0 = 0.f, a1 = 0.f, a2 = 0.f, a3 = 0.f;
#pragma unroll
        for (int j = 0; j < 32; ++j) {
          const u32x2 v = pf[j];
          a0 = fmaf(prr[j], bf2f((u16)(v[0] & 0xffffu)), a0);
          a1 = fmaf(prr[j], bf2f((u16)(v[0] >> 16)), a1);
          a2 = fmaf(prr[j], bf2f((u16)(v[1] & 0xffffu)), a2);
          a3 = fmaf(prr[j], bf2f((u16)(v[1] >> 16)), a3);
        }
        float* PLw = PL + w * 260 + lane * 4;
        PLw[0] = a0; PLw[1] = a1; PLw[2] = a2; PLw[3] = a3;
        __syncthreads();
        if (tid < 64) {
          const int cl = tid * 4;
          f32x4 s8 = (f32x4){0.f, 0.f, 0.f, 0.f};
#pragma unroll
          for (int ww = 0; ww < 8; ++ww) {
            s8[0] += PL[ww * 260 + cl];
            s8[1] += PL[ww * 260 + cl + 1];
            s8[2] += PL[ww * 260 + cl + 2];
            s8[3] += PL[ww * 260 + cl + 3];
          }
          const f32x4 ep4 = ldcg_f4(EPB + (size_t)b * 512 + chalf * 256 + cl);
          float xv[4];
#pragma unroll
          for (int r = 0; r < 4; ++r)
            xv[r] = fmaxf(ep4[r] + s8[r] * inv, 0.f);
          u32x2 xo;
          xo[0] = pk2(xv[0], xv[1]);
          xo[1] = pk2(xv[2], xv[3]);
          stcg_b8(XB + (size_t)b * 512 + chalf * 256 + cl, xo);
        }
      }
      if (chalf == 0 && s >= 1 && tid == 0) {
        const int tg = p.tags[(s - 1) * 128 + b];
        const float em = ldcg_f(EMB + (size_t)b * 256 + tg);
        const float ne = ldcg_f(NEB + b);
        stcg_f(NEB + b, ne + em);
      }
    }
    gbar2(bar, gen++, grp);

    // ================= P3 =================
    f32x4 R, Z, N;
    const bool giact = (s < 256) && (w == 0 || w == 2);
    if (giact) {
      const int r0 = (blk >> 3) * 16, b0 = (blk & 7) * 16;
      const int kh = w >> 1;
      if (kh == 0) {
        const float4 b1 = *(const float4*)(p.bih + r0 + kg * 4);
        const float4 b2 = *(const float4*)(p.bih + 512 + r0 + kg * 4);
        const float4 b3 = *(const float4*)(p.bih + 1024 + r0 + kg * 4);
        R[0] = b1.x; R[1] = b1.y; R[2] = b1.z; R[3] = b1.w;
        Z[0] = b2.x; Z[1] = b2.y; Z[2] = b2.z; Z[3] = b2.w;
        N[0] = b3.x; N[1] = b3.y; N[2] = b3.z; N[3] = b3.w;
      } else {
        R = (f32x4){0.f, 0.f, 0.f, 0.f}; Z = R; N = R;
      }
      u32x4 Xf[8];
      ldcg8(Xf, XB + (size_t)(b0 + bq) * 512 + kh * 256 + kg * 8);
      const u16* ArR = WIH16 + (size_t)(r0 + bq) * 512 + kh * 256 + kg * 8;
      const u16* ArZ = ArR + (size_t)512 * 512;
      const u16* ArN = ArR + (size_t)1024 * 512;
#pragma unroll
      for (int kt = 0; kt < 8; ++kt) {
        const short8 bb = __builtin_bit_cast(short8, Xf[kt]);
        R = MFMA16(*(const short8*)(ArR + kt * 32), bb, R);
        Z = MFMA16(*(const short8*)(ArZ + kt * 32), bb, Z);
        N = MFMA16(*(const short8*)(ArN + kt * 32), bb, N);
      }
      if (w == 2) {
#pragma unroll
        for (int r = 0; r < 4; ++r) {
          pr3[0][(kg * 4 + r) * 16 + bq] = R[r];
          pr3[1][(kg * 4 + r) * 16 + bq] = Z[r];
          pr3[2][(kg * 4 + r) * 16 + bq] = N[r];
        }
      }
    }
    __syncthreads();
    if (s < 256 && w == 0) {  // combine + gates + h_new
      const int r0 = (blk >> 3) * 16, b0 = (blk & 7) * 16;
      const int b = b0 + bq;
      f32x4 gr4, gz4, gn4;
      ldcg_f4x3(gr4, gz4, gn4,
                GHB + (size_t)b * 1536 + r0 + kg * 4,
                GHB + (size_t)b * 1536 + 512 + r0 + kg * 4,
                GHB + (size_t)b * 1536 + 1024 + r0 + kg * 4);
      const u32x2 h4 = ldcg_b8(HB + (size_t)b * 512 + r0 + kg * 4);
      const float hold[4] = {bf2f((u16)(h4[0] & 0xffffu)), bf2f((u16)(h4[0] >> 16)),
                             bf2f((u16)(h4[1] & 0xffffu)), bf2f((u16)(h4[1] >> 16))};
      float hn[4];
#pragma unroll
      for (int r = 0; r < 4; ++r) {
        const float Rv = R[r] + pr3[0][(kg * 4 + r) * 16 + bq];
        const float Zv = Z[r] + pr3[1][(kg * 4 + r) * 16 + bq];
        const float Nv = N[r] + pr3[2][(kg * 4 + r) * 16 + bq];
        const float rr = 1.f / (1.f + __expf(-(Rv + gr4[r])));
        const float zz = 1.f / (1.f + __expf(-(Zv + gz4[r])));
        const float nn = tanhf(Nv + rr * gn4[r]);
        hn[r] = (1.f - zz) * nn + zz * hold[r];
      }
      u32x2 ho;
      ho[0] = pk2(hn[0], hn[1]);
      ho[1] = pk2(hn[2], hn[3]);
      stcg_b8(HB + (size_t)b * 512 + r0 + kg * 4, ho);
    }
    if (w == 1) {
      if (blk < 128) {
        if (s >= 1) {  // CRF-B
          const int kn0 = (blk >> 3) * 16, b0 = (blk & 7) * 16;
          const int b = b0 + bq;
          if (s == 1) {
            const f32x4 e4 = ldcg_f4(EMB + (size_t)b * 256 + kn0 + kg * 4);
            const float4 c4 = *(const float4*)(p.cs + kn0 + kg * 4);
            f32x4 o;
            o[0] = c4.x + e4[0]; o[1] = c4.y + e4[1];
            o[2] = c4.z + e4[2]; o[3] = c4.w + e4[3];
            stcg_f4(SRB + (size_t)b * 256 + kn0 + kg * 4, o);
          } else {
            f32x4 acc = (f32x4){0.f, 0.f, 0.f, 0.f};
            u32x4 Pf[8];
            ldcg8(Pf, PBu + (size_t)(b0 + bq) * 256 + kg * 8);
            const u16* Ar = WXT16 + (size_t)(kn0 + bq) * 256 + kg * 8;
#pragma unroll
            for (int kt = 0; kt < 8; ++kt)
              acc = MFMA16(*(const short8*)(Ar + kt * 32),
                           __builtin_bit_cast(short8, Pf[kt]), acc);
            const float mf = ldcg_f(MFB + b);
            const f32x4 e4 = ldcg_f4(EMB + (size_t)b * 256 + kn0 + kg * 4);
            f32x4 o;
            o[0] = mf + __logf(acc[0]) + e4[0];
            o[1] = mf + __logf(acc[1]) + e4[1];
            o[2] = mf + __logf(acc[2]) + e4[2];
            o[3] = mf + __logf(acc[3]) + e4[3];
            stcg_f4(SRB + (size_t)b * 256 + kn0 + kg * 4, o);
          }
        }
      } else {
        if (s < 255) {  // stage e_{s+1}
          const int b = blk - 128;
          const int tok = p.tags[s * 128 + b];
          const float4 ev = *(const float4*)(p.emb + (size_t)tok * 256 + lane * 4);
          u32x2 ee;
          ee[0] = pk2(ev.x, ev.y);
          ee[1] = pk2(ev.z, ev.w);
          stcg_b8(EB + (size_t)b * 256 + lane * 4, ee);
        }
      }
    }
    gbar2(bar, gen++, grp);
  }
}

// ---------------- final ----------------
__global__ void __launch_bounds__(128) kFinal(const float* __restrict__ ws,
                                              const float* __restrict__ ce,
                                              float* __restrict__ out) {
  __shared__ float acc[128];
  const int tid = threadIdx.x;
  const float* SRB = ws + F_SRB;
  float mx = -3.0e38f;
#pragma unroll 8
  for (int k = 0; k < 256; ++k) mx = fmaxf(mx, SRB[(size_t)tid * 256 + k] + ce[k]);
  float sm = 0.f;
#pragma unroll 8
  for (int k = 0; k < 256; ++k) sm += __expf(SRB[(size_t)tid * 256 + k] + ce[k] - mx);
  acc[tid] = ws[F_NSB + tid] + ws[F_NEB + tid] - (mx + __logf(sm));
  __syncthreads();
  if (tid < 64) {
    float v = acc[tid] + acc[tid + 64];
#pragma unroll
    for (int o = 32; o; o >>= 1) v += __shfl_xor(v, o);
    if (tid == 0) out[0] = v * (1.f / 128.f);
  }
}

extern "C" void kernel_launch(void* const* d_in, const int* in_sizes, int n_in,
                              void* d_out, int out_size, void* d_ws, size_t ws_size,
                              hipStream_t stream) {
  (void)in_sizes; (void)n_in; (void)out_size; (void)ws_size;
  const int* dec = (const int*)d_in[0];
  const int* tags = (const int*)d_in[1];
  const float* enc = (const float*)d_in[2];
  const float* emb = (const float*)d_in[3];
  const float* aW = (const float*)d_in[4];
  const float* ab = (const float*)d_in[5];
  const float* cW = (const float*)d_in[6];
  const float* cb = (const float*)d_in[7];
  const float* wih = (const float*)d_in[8];
  const float* whh = (const float*)d_in[9];
  const float* bih = (const float*)d_in[10];
  const float* bhh = (const float*)d_in[11];
  const float* oW = (const float*)d_in[12];
  const float* ob = (const float*)d_in[13];
  const float* cs = (const float*)d_in[14];
  const float* ce = (const float*)d_in[15];
  const float* ct = (const float*)d_in[16];
  float* ws = (float*)d_ws;
  float* out = (float*)d_out;

  kPrep<<<dim3(8192), dim3(256), 0, stream>>>(wih, whh, aW, oW, cW, ct, ws);
  kInit<<<dim3(256), dim3(256), 0, stream>>>(dec, tags, emb, cs, ce, ct, ws);
  kEncW<<<dim3(2048), dim3(256), 0, stream>>>(enc, cW, (u16*)d_ws);

  P9 p;
  p.dec = dec; p.tags = tags; p.emb = emb;
  p.ab = ab; p.cb = cb; p.bih = bih; p.bhh = bhh;
  p.ob = ob; p.cs = cs; p.ws = ws;
  void* args[] = { &p };
  hipLaunchCooperativeKernel((void*)maink, dim3(256), dim3(512), args, 0, stream);

  kFinal<<<dim3(1), dim3(128), 0, stream>>>(ws, ce, out);
}

// Round 10
// 8384.051 us; speedup vs baseline: 1.4383x; 1.4383x over previous
//
#include <hip/hip_runtime.h>

// Round 10: R7 verbatim EXCEPT the P2 encT stream uses plain cached loads
// (was nontemporal). encT (32MB) then lives in Infinity Cache instead of
// re-fetching 33MB/step from HBM. Single-variable A/B vs R7 (8.68ms).

typedef unsigned short u16;
typedef unsigned int u32;
typedef __attribute__((ext_vector_type(8))) short short8;
typedef __attribute__((ext_vector_type(4))) float f32x4;
typedef __attribute__((ext_vector_type(4))) u32 u32x4;
typedef __attribute__((ext_vector_type(2))) u32 u32x2;

#define MFMA16(a, b, c) __builtin_amdgcn_mfma_f32_16x16x32_bf16((a), (b), (c), 0, 0, 0)

// ---- ws layout ----
#define U_ENC 0u           // encT bf16 [128 b][256 t][512 c]  (32MB)
#define U_WHH 16777216u    // [1536][512]
#define U_WIH 17563648u    // [1536][512]
#define U_WAW 18350080u    // [256][768]
#define U_WOW 18546688u    // [256][512]
#define U_WCE 18677760u    // [512][256]
#define U_WXT 18808832u    // [256][256]
#define U_HB  18874368u    // h bf16 [128][512]
#define U_EB  18939904u    // e bf16 [128][256]
#define U_XB  18972672u    // x bf16 [128][512]
#define U_PB  19038208u    // p bf16 [128][256]
#define F_LGB 9535488u
#define F_EMB 9568256u
#define F_EPB 9601024u
#define F_GHB 9666560u
#define F_SRB 9863168u
#define F_MFB 9895936u
#define F_NEB 9896064u
#define F_NSB 9896192u
#define F_BAR 9896448u     // u32: L1[771][16]x16 (197376) + REL[771]
#define BAR_N 198147u

__device__ __forceinline__ float bf2f(u16 u) { return __uint_as_float(((u32)u) << 16); }
__device__ __forceinline__ u16 f2bf(float f) {
  u32 u = __float_as_uint(f);
  return (u16)((u + 0x7FFFu + ((u >> 16) & 1u)) >> 16);
}
__device__ __forceinline__ u32 pk2(float a, float b) {
  return (u32)f2bf(a) | ((u32)f2bf(b) << 16);
}

// ---- coherent (sc0 sc1) load/store helpers ----
__device__ __forceinline__ float ldcg_f(const float* p) {
  float r;
  asm volatile("global_load_dword %0, %1, off sc0 sc1\n\ts_waitcnt vmcnt(0)"
               : "=v"(r) : "v"(p));
  return r;
}
__device__ __forceinline__ f32x4 ldcg_f4(const float* p) {
  f32x4 r;
  asm volatile("global_load_dwordx4 %0, %1, off sc0 sc1\n\ts_waitcnt vmcnt(0)"
               : "=v"(r) : "v"(p));
  return r;
}
__device__ __forceinline__ u32x2 ldcg_b8(const u16* p) {
  u32x2 r;
  asm volatile("global_load_dwordx2 %0, %1, off sc0 sc1\n\ts_waitcnt vmcnt(0)"
               : "=v"(r) : "v"(p));
  return r;
}
__device__ __forceinline__ void ldcg_f4x3(f32x4& a, f32x4& b, f32x4& c,
                                          const float* p0, const float* p1,
                                          const float* p2) {
  asm volatile(
      "global_load_dwordx4 %0, %3, off sc0 sc1\n\t"
      "global_load_dwordx4 %1, %4, off sc0 sc1\n\t"
      "global_load_dwordx4 %2, %5, off sc0 sc1\n\t"
      "s_waitcnt vmcnt(0)"
      : "=&v"(a), "=&v"(b), "=&v"(c)
      : "v"(p0), "v"(p1), "v"(p2));
}
__device__ __forceinline__ void ldcg8(u32x4 d[8], const u16* p) {
  asm volatile(
      "global_load_dwordx4 %0, %8, off sc0 sc1\n\t"
      "global_load_dwordx4 %1, %8, off offset:64 sc0 sc1\n\t"
      "global_load_dwordx4 %2, %8, off offset:128 sc0 sc1\n\t"
      "global_load_dwordx4 %3, %8, off offset:192 sc0 sc1\n\t"
      "global_load_dwordx4 %4, %8, off offset:256 sc0 sc1\n\t"
      "global_load_dwordx4 %5, %8, off offset:320 sc0 sc1\n\t"
      "global_load_dwordx4 %6, %8, off offset:384 sc0 sc1\n\t"
      "global_load_dwordx4 %7, %8, off offset:448 sc0 sc1\n\t"
      "s_waitcnt vmcnt(0)"
      : "=&v"(d[0]), "=&v"(d[1]), "=&v"(d[2]), "=&v"(d[3]),
        "=&v"(d[4]), "=&v"(d[5]), "=&v"(d[6]), "=&v"(d[7])
      : "v"(p));
}
__device__ __forceinline__ void ldcg16(u32x4 d[16], const u16* p) {
  asm volatile(
      "global_load_dwordx4 %0, %16, off sc0 sc1\n\t"
      "global_load_dwordx4 %1, %16, off offset:64 sc0 sc1\n\t"
      "global_load_dwordx4 %2, %16, off offset:128 sc0 sc1\n\t"
      "global_load_dwordx4 %3, %16, off offset:192 sc0 sc1\n\t"
      "global_load_dwordx4 %4, %16, off offset:256 sc0 sc1\n\t"
      "global_load_dwordx4 %5, %16, off offset:320 sc0 sc1\n\t"
      "global_load_dwordx4 %6, %16, off offset:384 sc0 sc1\n\t"
      "global_load_dwordx4 %7, %16, off offset:448 sc0 sc1\n\t"
      "global_load_dwordx4 %8, %16, off offset:512 sc0 sc1\n\t"
      "global_load_dwordx4 %9, %16, off offset:576 sc0 sc1\n\t"
      "global_load_dwordx4 %10, %16, off offset:640 sc0 sc1\n\t"
      "global_load_dwordx4 %11, %16, off offset:704 sc0 sc1\n\t"
      "global_load_dwordx4 %12, %16, off offset:768 sc0 sc1\n\t"
      "global_load_dwordx4 %13, %16, off offset:832 sc0 sc1\n\t"
      "global_load_dwordx4 %14, %16, off offset:896 sc0 sc1\n\t"
      "global_load_dwordx4 %15, %16, off offset:960 sc0 sc1\n\t"
      "s_waitcnt vmcnt(0)"
      : "=&v"(d[0]), "=&v"(d[1]), "=&v"(d[2]), "=&v"(d[3]),
        "=&v"(d[4]), "=&v"(d[5]), "=&v"(d[6]), "=&v"(d[7]),
        "=&v"(d[8]), "=&v"(d[9]), "=&v"(d[10]), "=&v"(d[11]),
        "=&v"(d[12]), "=&v"(d[13]), "=&v"(d[14]), "=&v"(d[15])
      : "v"(p));
}
__device__ __forceinline__ void stcg_f(float* p, float v) {
  asm volatile("global_store_dword %0, %1, off sc0 sc1" ::"v"(p), "v"(v) : "memory");
}
__device__ __forceinline__ void stcg_f4(float* p, f32x4 v) {
  asm volatile("global_store_dwordx4 %0, %1, off sc0 sc1" ::"v"(p), "v"(v) : "memory");
}
__device__ __forceinline__ void stcg_b8(u16* p, u32x2 v) {
  asm volatile("global_store_dwordx2 %0, %1, off sc0 sc1" ::"v"(p), "v"(v) : "memory");
}

// ---- two-level generation-indexed grid barrier (no fences, no L2 flush) ----
__device__ __forceinline__ void gbar2(u32* bar, u32 gen, int grp) {
  __syncthreads();  // drains vmcnt -> write-through stores visible
  if (threadIdx.x == 0) {
    u32* l1 = bar + ((size_t)gen * 16u + (u32)grp) * 16u;
    u32* rel = bar + 197376u + gen;
    const u32 old = __hip_atomic_fetch_add(l1, 1u, __ATOMIC_RELAXED,
                                           __HIP_MEMORY_SCOPE_AGENT);
    if (old == 15u)
      __hip_atomic_fetch_add(rel, 1u, __ATOMIC_RELAXED, __HIP_MEMORY_SCOPE_AGENT);
    while (__hip_atomic_load(rel, __ATOMIC_RELAXED, __HIP_MEMORY_SCOPE_AGENT) < 16u) {}
  }
  __syncthreads();
}

// ---------------- weight convert to bf16 ----------------
__global__ void __launch_bounds__(256) kPrep(const float* __restrict__ wih,
                                             const float* __restrict__ whh,
                                             const float* __restrict__ aW,
                                             const float* __restrict__ oW,
                                             const float* __restrict__ cW,
                                             const float* __restrict__ ct,
                                             float* __restrict__ ws) {
  u16* W = (u16*)ws;
  const u32 i = blockIdx.x * 256 + threadIdx.x;
  if (i < 786432u) {
    W[U_WHH + i] = f2bf(whh[i]);
  } else if (i < 1572864u) {
    const u32 j = i - 786432u;
    W[U_WIH + j] = f2bf(wih[j]);
  } else if (i < 1769472u) {
    const u32 j = i - 1572864u;
    W[U_WAW + j] = f2bf(aW[j]);
  } else if (i < 1900544u) {
    const u32 j = i - 1769472u;
    W[U_WOW + j] = f2bf(oW[j]);
  } else if (i < 2031616u) {
    const u32 j = i - 1900544u;
    W[U_WCE + j] = f2bf(cW[(size_t)(j >> 8) * 1280 + (j & 255u)]);
  } else {
    const u32 j = i - 2031616u;
    const u32 kn = j >> 8, k = j & 255u;
    W[U_WXT + j] = f2bf(__expf(ct[k * 256u + kn]));
  }
}

// ---------------- init ----------------
__global__ void __launch_bounds__(256) kInit(const int* __restrict__ dec,
                                             const int* __restrict__ tags,
                                             const float* __restrict__ emb,
                                             const float* __restrict__ cs,
                                             const float* __restrict__ ce,
                                             const float* __restrict__ ct,
                                             float* __restrict__ ws) {
  const u32 idx = blockIdx.x * 256 + threadIdx.x;  // 65536
  u16* ENC = (u16*)ws;
  u16* HB = ENC + U_HB;
  u16* EB = ENC + U_EB;
  if (idx < 32768u) {
    ((u32*)HB)[idx] = 0u;
    const int b = idx >> 8, j = idx & 255;
    EB[idx] = f2bf(emb[(size_t)dec[b] * 256 + j]);
  }
  if (idx < 128u) {
    int prev = tags[idx];
    float a = cs[prev];
    for (int t = 1; t < 256; ++t) {
      const int cur = tags[t * 128 + idx];
      a += ct[prev * 256 + cur];
      prev = cur;
    }
    ws[F_NSB + idx] = a + ce[prev];
    ws[F_NEB + idx] = 0.f;
  }
  u32* bar = (u32*)(ws + F_BAR);
  if (idx < 49537u) {
#pragma unroll
    for (int j = 0; j < 4; ++j) {
      const u32 k = idx * 4u + (u32)j;
      if (k < BAR_N) bar[k] = 0u;
    }
  }
}

// ---------------- encT[b][t][c] = sum_j enc[t,b,j] * comb_W[c, 256+j] ----------------
__global__ void __launch_bounds__(256) kEncW(const float* __restrict__ enc,
                                             const float* __restrict__ cW,
                                             u16* __restrict__ encT) {
  __shared__ float wL[64 * 64];
  const int t = blockIdx.x >> 3, cblk = blockIdx.x & 7;
  const int tid = threadIdx.x;
  const int bg = tid & 31;
  const int cg = tid >> 5;
  float acc[4][8];
#pragma unroll
  for (int i = 0; i < 4; ++i)
#pragma unroll
    for (int c = 0; c < 8; ++c) acc[i][c] = 0.f;
  const float* encB = enc + (size_t)t * (128 * 1024);
  for (int jt = 0; jt < 16; ++jt) {
    const int j0 = jt * 64;
    __syncthreads();
    for (int i = tid; i < 4096; i += 256) {
      const int cc = i >> 6, jj = i & 63;
      wL[cc * 64 + jj] = cW[(size_t)(cblk * 64 + cc) * 1280 + 256 + j0 + jj];
    }
    __syncthreads();
    for (int jj = 0; jj < 64; ++jj) {
      const float e0 = encB[(bg * 4 + 0) * 1024 + j0 + jj];
      const float e1 = encB[(bg * 4 + 1) * 1024 + j0 + jj];
      const float e2 = encB[(bg * 4 + 2) * 1024 + j0 + jj];
      const float e3 = encB[(bg * 4 + 3) * 1024 + j0 + jj];
#pragma unroll
      for (int c = 0; c < 8; ++c) {
        const float wv = wL[(cg * 8 + c) * 64 + jj];
        acc[0][c] = fmaf(e0, wv, acc[0][c]);
        acc[1][c] = fmaf(e1, wv, acc[1][c]);
        acc[2][c] = fmaf(e2, wv, acc[2][c]);
        acc[3][c] = fmaf(e3, wv, acc[3][c]);
      }
    }
  }
#pragma unroll
  for (int i = 0; i < 4; ++i)
    for (int c = 0; c < 8; ++c) {
      const int b = bg * 4 + i, cc = cblk * 64 + cg * 8 + c;
      encT[(size_t)b * 131072u + (size_t)t * 512u + cc] = f2bf(acc[i][c]);
    }
}

struct P9 {
  const int* dec; const int* tags; const float* emb;
  const float* ab; const float* cb; const float* bih; const float* bhh;
  const float* ob; const float* cs;
  float* ws;
};

// ---------------- main cooperative kernel ----------------
__global__ void __launch_bounds__(512, 2) maink(P9 p) {
  float* const ws = p.ws;
  u16* const ENC = (u16*)ws;
  const u16* const WHH16 = ENC + U_WHH;
  const u16* const WIH16 = ENC + U_WIH;
  const u16* const WAW16 = ENC + U_WAW;
  const u16* const WOW16 = ENC + U_WOW;
  const u16* const WCE16 = ENC + U_WCE;
  const u16* const WXT16 = ENC + U_WXT;
  u16* const HB = ENC + U_HB;
  u16* const EB = ENC + U_EB;
  u16* const XB = ENC + U_XB;
  u16* const PBu = ENC + U_PB;
  float* const LGB = ws + F_LGB;
  float* const EMB = ws + F_EMB;
  float* const EPB = ws + F_EPB;
  float* const GHB = ws + F_GHB;
  float* const SRB = ws + F_SRB;
  float* const MFB = ws + F_MFB;
  float* const NEB = ws + F_NEB;
  u32* const bar = (u32*)(ws + F_BAR);

  __shared__ float prL[256];
  __shared__ float pacc[4][256];
  __shared__ float red[16];
  __shared__ float pr3[3][256];

  const int tid = threadIdx.x;
  const int w = tid >> 6, lane = tid & 63;
  const int bq = lane & 15, kg = lane >> 4;
  const int blk = blockIdx.x;
  const int grp = blk >> 4;
  u32 gen = 0;

  for (int s = 0; s <= 256; ++s) {
    // ================= P1 =================
    if (w < 3) {
      if (s < 256) {  // gh: t = w*256+blk in [0,768)
        const int t = w * 256 + blk;
        const int r0 = (t >> 3) * 16, b0 = (t & 7) * 16;
        f32x4 acc;
        const float4 bs = *(const float4*)(p.bhh + r0 + kg * 4);
        acc[0] = bs.x; acc[1] = bs.y; acc[2] = bs.z; acc[3] = bs.w;
        u32x4 Bf[16];
        ldcg16(Bf, HB + (size_t)(b0 + bq) * 512 + kg * 8);
        const u16* Ar = WHH16 + (size_t)(r0 + bq) * 512 + kg * 8;
#pragma unroll
        for (int kt = 0; kt < 16; ++kt)
          acc = MFMA16(*(const short8*)(Ar + kt * 32),
                       __builtin_bit_cast(short8, Bf[kt]), acc);
        stcg_f4(GHB + (size_t)(b0 + bq) * 1536 + r0 + kg * 4, acc);
      }
    } else if (w == 3) {
      if (blk < 128) {
        if (s < 256) {  // attn logits, K=768
          const int r0 = (blk >> 3) * 16, b0 = (blk & 7) * 16;
          f32x4 acc;
          const float4 bs = *(const float4*)(p.ab + r0 + kg * 4);
          acc[0] = bs.x; acc[1] = bs.y; acc[2] = bs.z; acc[3] = bs.w;
          u32x4 Ef[8], Hf[16];
          ldcg8(Ef, EB + (size_t)(b0 + bq) * 256 + kg * 8);
          ldcg16(Hf, HB + (size_t)(b0 + bq) * 512 + kg * 8);
          const u16* Ar = WAW16 + (size_t)(r0 + bq) * 768 + kg * 8;
#pragma unroll
          for (int kt = 0; kt < 8; ++kt)
            acc = MFMA16(*(const short8*)(Ar + kt * 32),
                         __builtin_bit_cast(short8, Ef[kt]), acc);
#pragma unroll
          for (int kt = 0; kt < 16; ++kt)
            acc = MFMA16(*(const short8*)(Ar + 256 + kt * 32),
                         __builtin_bit_cast(short8, Hf[kt]), acc);
          stcg_f4(LGB + (size_t)(b0 + bq) * 256 + r0 + kg * 4, acc);
        }
      } else {
        if (s >= 1) {  // em_{s-1} from current h
          const int t2 = blk - 128;
          const int r0 = (t2 >> 3) * 16, b0 = (t2 & 7) * 16;
          f32x4 acc;
          const float4 bs = *(const float4*)(p.ob + r0 + kg * 4);
          acc[0] = bs.x; acc[1] = bs.y; acc[2] = bs.z; acc[3] = bs.w;
          u32x4 Hf[16];
          ldcg16(Hf, HB + (size_t)(b0 + bq) * 512 + kg * 8);
          const u16* Ar = WOW16 + (size_t)(r0 + bq) * 512 + kg * 8;
#pragma unroll
          for (int kt = 0; kt < 16; ++kt)
            acc = MFMA16(*(const short8*)(Ar + kt * 32),
                         __builtin_bit_cast(short8, Hf[kt]), acc);
          stcg_f4(EMB + (size_t)(b0 + bq) * 256 + r0 + kg * 4, acc);
        }
      }
    } else if (w == 4) {
      if (s < 256) {  // ep = cb + cWe @ e
        const int r0 = (blk >> 3) * 16, b0 = (blk & 7) * 16;
        f32x4 acc;
        const float4 bs = *(const float4*)(p.cb + r0 + kg * 4);
        acc[0] = bs.x; acc[1] = bs.y; acc[2] = bs.z; acc[3] = bs.w;
        u32x4 Ef[8];
        ldcg8(Ef, EB + (size_t)(b0 + bq) * 256 + kg * 8);
        const u16* Ar = WCE16 + (size_t)(r0 + bq) * 256 + kg * 8;
#pragma unroll
        for (int kt = 0; kt < 8; ++kt)
          acc = MFMA16(*(const short8*)(Ar + kt * 32),
                       __builtin_bit_cast(short8, Ef[kt]), acc);
        stcg_f4(EPB + (size_t)(b0 + bq) * 512 + r0 + kg * 4, acc);
      }
    } else if (w == 5) {
      if (blk < 128 && s >= 2) {  // CRF-A
        const int b = blk;
        const f32x4 sv = ldcg_f4(SRB + (size_t)b * 256 + lane * 4);
        float mx = fmaxf(fmaxf(sv[0], sv[1]), fmaxf(sv[2], sv[3]));
#pragma unroll
        for (int o = 32; o; o >>= 1) mx = fmaxf(mx, __shfl_xor(mx, o));
        u32x2 pv;
        pv[0] = pk2(__expf(sv[0] - mx), __expf(sv[1] - mx));
        pv[1] = pk2(__expf(sv[2] - mx), __expf(sv[3] - mx));
        stcg_b8(PBu + (size_t)b * 256 + lane * 4, pv);
        if (lane == 0) stcg_f(MFB + b, mx);
      }
    }
    gbar2(bar, gen++, grp);

    // ================= P2 (256 blocks: b = blk&127, c-half = blk>>7) =================
    {
      const int b = blk & 127, chalf = blk >> 7;
      if (s < 256) {
        float v = -3.0e38f;
        if (tid < 256) v = ldcg_f(LGB + (size_t)b * 256 + tid);
        float m = v;
#pragma unroll
        for (int o = 32; o; o >>= 1) m = fmaxf(m, __shfl_xor(m, o));
        if (lane == 0) red[w] = m;
        __syncthreads();
        float mB = red[0];
#pragma unroll
        for (int q = 1; q < 8; ++q) mB = fmaxf(mB, red[q]);
        float e = 0.f;
        if (tid < 256) { e = __expf(v - mB); prL[tid] = e; }
        float sacc = e;
#pragma unroll
        for (int o = 32; o; o >>= 1) sacc += __shfl_xor(sacc, o);
        if (lane == 0) red[8 + w] = sacc;
        __syncthreads();
        float sum = red[8];
#pragma unroll
        for (int q = 1; q < 8; ++q) sum += red[8 + q];
        const float inv = 1.f / sum;
        // CACHED stream of this block's c-half (allocates in Infinity Cache)
        const int tq = tid >> 7, cp = tid & 127;
        const int c0l = cp * 2;
        const u16* base = ENC + (size_t)b * 131072u + (size_t)(tq * 64) * 512u +
                          (chalf * 256 + c0l);
        const float* prh = prL + tq * 64;
        float a0 = 0.f, a1 = 0.f;
#pragma unroll 8
        for (int t = 0; t < 64; ++t) {
          const float prt = prh[t];
          const u32 vv = *(const u32*)(base + (size_t)t * 512);
          a0 = fmaf(prt, bf2f((u16)(vv & 0xffffu)), a0);
          a1 = fmaf(prt, bf2f((u16)(vv >> 16)), a1);
        }
        pacc[tq][c0l] = a0;
        pacc[tq][c0l + 1] = a1;
        __syncthreads();
        if (tid < 64) {
          const int cl = tid * 4;
          const f32x4 ep4 = ldcg_f4(EPB + (size_t)b * 512 + chalf * 256 + cl);
          float xv[4];
#pragma unroll
          for (int r = 0; r < 4; ++r)
            xv[r] = fmaxf(ep4[r] + (pacc[0][cl + r] + pacc[1][cl + r] +
                                    pacc[2][cl + r] + pacc[3][cl + r]) * inv, 0.f);
          u32x2 xo;
          xo[0] = pk2(xv[0], xv[1]);
          xo[1] = pk2(xv[2], xv[3]);
          stcg_b8(XB + (size_t)b * 512 + chalf * 256 + cl, xo);
        }
      }
      if (chalf == 0 && s >= 1 && tid == 0) {
        const int tg = p.tags[(s - 1) * 128 + b];
        const float em = ldcg_f(EMB + (size_t)b * 256 + tg);
        const float ne = ldcg_f(NEB + b);
        stcg_f(NEB + b, ne + em);
      }
    }
    gbar2(bar, gen++, grp);

    // ================= P3 =================
    f32x4 R, Z, N;
    const bool giact = (s < 256) && (w == 0 || w == 2);
    if (giact) {
      const int r0 = (blk >> 3) * 16, b0 = (blk & 7) * 16;
      const int kh = w >> 1;
      if (kh == 0) {
        const float4 b1 = *(const float4*)(p.bih + r0 + kg * 4);
        const float4 b2 = *(const float4*)(p.bih + 512 + r0 + kg * 4);
        const float4 b3 = *(const float4*)(p.bih + 1024 + r0 + kg * 4);
        R[0] = b1.x; R[1] = b1.y; R[2] = b1.z; R[3] = b1.w;
        Z[0] = b2.x; Z[1] = b2.y; Z[2] = b2.z; Z[3] = b2.w;
        N[0] = b3.x; N[1] = b3.y; N[2] = b3.z; N[3] = b3.w;
      } else {
        R = (f32x4){0.f, 0.f, 0.f, 0.f}; Z = R; N = R;
      }
      u32x4 Xf[8];
      ldcg8(Xf, XB + (size_t)(b0 + bq) * 512 + kh * 256 + kg * 8);
      const u16* ArR = WIH16 + (size_t)(r0 + bq) * 512 + kh * 256 + kg * 8;
      const u16* ArZ = ArR + (size_t)512 * 512;
      const u16* ArN = ArR + (size_t)1024 * 512;
#pragma unroll
      for (int kt = 0; kt < 8; ++kt) {
        const short8 bb = __builtin_bit_cast(short8, Xf[kt]);
        R = MFMA16(*(const short8*)(ArR + kt * 32), bb, R);
        Z = MFMA16(*(const short8*)(ArZ + kt * 32), bb, Z);
        N = MFMA16(*(const short8*)(ArN + kt * 32), bb, N);
      }
      if (w == 2) {
#pragma unroll
        for (int r = 0; r < 4; ++r) {
          pr3[0][(kg * 4 + r) * 16 + bq] = R[r];
          pr3[1][(kg * 4 + r) * 16 + bq] = Z[r];
          pr3[2][(kg * 4 + r) * 16 + bq] = N[r];
        }
      }
    }
    __syncthreads();
    if (s < 256 && w == 0) {  // combine + gates + h_new
      const int r0 = (blk >> 3) * 16, b0 = (blk & 7) * 16;
      const int b = b0 + bq;
      f32x4 gr4, gz4, gn4;
      ldcg_f4x3(gr4, gz4, gn4,
                GHB + (size_t)b * 1536 + r0 + kg * 4,
                GHB + (size_t)b * 1536 + 512 + r0 + kg * 4,
                GHB + (size_t)b * 1536 + 1024 + r0 + kg * 4);
      const u32x2 h4 = ldcg_b8(HB + (size_t)b * 512 + r0 + kg * 4);
      const float hold[4] = {bf2f((u16)(h4[0] & 0xffffu)), bf2f((u16)(h4[0] >> 16)),
                             bf2f((u16)(h4[1] & 0xffffu)), bf2f((u16)(h4[1] >> 16))};
      float hn[4];
#pragma unroll
      for (int r = 0; r < 4; ++r) {
        const float Rv = R[r] + pr3[0][(kg * 4 + r) * 16 + bq];
        const float Zv = Z[r] + pr3[1][(kg * 4 + r) * 16 + bq];
        const float Nv = N[r] + pr3[2][(kg * 4 + r) * 16 + bq];
        const float rr = 1.f / (1.f + __expf(-(Rv + gr4[r])));
        const float zz = 1.f / (1.f + __expf(-(Zv + gz4[r])));
        const float nn = tanhf(Nv + rr * gn4[r]);
        hn[r] = (1.f - zz) * nn + zz * hold[r];
      }
      u32x2 ho;
      ho[0] = pk2(hn[0], hn[1]);
      ho[1] = pk2(hn[2], hn[3]);
      stcg_b8(HB + (size_t)b * 512 + r0 + kg * 4, ho);
    }
    if (w == 1) {
      if (blk < 128) {
        if (s >= 1) {  // CRF-B
          const int kn0 = (blk >> 3) * 16, b0 = (blk & 7) * 16;
          const int b = b0 + bq;
          if (s == 1) {
            const f32x4 e4 = ldcg_f4(EMB + (size_t)b * 256 + kn0 + kg * 4);
            const float4 c4 = *(const float4*)(p.cs + kn0 + kg * 4);
            f32x4 o;
            o[0] = c4.x + e4[0]; o[1] = c4.y + e4[1];
            o[2] = c4.z + e4[2]; o[3] = c4.w + e4[3];
            stcg_f4(SRB + (size_t)b * 256 + kn0 + kg * 4, o);
          } else {
            f32x4 acc = (f32x4){0.f, 0.f, 0.f, 0.f};
            u32x4 Pf[8];
            ldcg8(Pf, PBu + (size_t)(b0 + bq) * 256 + kg * 8);
            const u16* Ar = WXT16 + (size_t)(kn0 + bq) * 256 + kg * 8;
#pragma unroll
            for (int kt = 0; kt < 8; ++kt)
              acc = MFMA16(*(const short8*)(Ar + kt * 32),
                           __builtin_bit_cast(short8, Pf[kt]), acc);
            const float mf = ldcg_f(MFB + b);
            const f32x4 e4 = ldcg_f4(EMB + (size_t)b * 256 + kn0 + kg * 4);
            f32x4 o;
            o[0] = mf + __logf(acc[0]) + e4[0];
            o[1] = mf + __logf(acc[1]) + e4[1];
            o[2] = mf + __logf(acc[2]) + e4[2];
            o[3] = mf + __logf(acc[3]) + e4[3];
            stcg_f4(SRB + (size_t)b * 256 + kn0 + kg * 4, o);
          }
        }
      } else {
        if (s < 255) {  // stage e_{s+1}
          const int b = blk - 128;
          const int tok = p.tags[s * 128 + b];
          const float4 ev = *(const float4*)(p.emb + (size_t)tok * 256 + lane * 4);
          u32x2 ee;
          ee[0] = pk2(ev.x, ev.y);
          ee[1] = pk2(ev.z, ev.w);
          stcg_b8(EB + (size_t)b * 256 + lane * 4, ee);
        }
      }
    }
    gbar2(bar, gen++, grp);
  }
}

// ---------------- final: denominator + mean ----------------
__global__ void __launch_bounds__(128) kFinal(const float* __restrict__ ws,
                                              const float* __restrict__ ce,
                                              float* __restrict__ out) {
  __shared__ float acc[128];
  const int tid = threadIdx.x;  // 128
  const float* SRB = ws + F_SRB;
  float mx = -3.0e38f;
#pragma unroll 8
  for (int k = 0; k < 256; ++k) mx = fmaxf(mx, SRB[(size_t)tid * 256 + k] + ce[k]);
  float sm = 0.f;
#pragma unroll 8
  for (int k = 0; k < 256; ++k) sm += __expf(SRB[(size_t)tid * 256 + k] + ce[k] - mx);
  acc[tid] = ws[F_NSB + tid] + ws[F_NEB + tid] - (mx + __logf(sm));
  __syncthreads();
  if (tid < 64) {
    float v = acc[tid] + acc[tid + 64];
#pragma unroll
    for (int o = 32; o; o >>= 1) v += __shfl_xor(v, o);
    if (tid == 0) out[0] = v * (1.f / 128.f);
  }
}

extern "C" void kernel_launch(void* const* d_in, const int* in_sizes, int n_in,
                              void* d_out, int out_size, void* d_ws, size_t ws_size,
                              hipStream_t stream) {
  (void)in_sizes; (void)n_in; (void)out_size; (void)ws_size;
  const int* dec = (const int*)d_in[0];
  const int* tags = (const int*)d_in[1];
  const float* enc = (const float*)d_in[2];
  const float* emb = (const float*)d_in[3];
  const float* aW = (const float*)d_in[4];
  const float* ab = (const float*)d_in[5];
  const float* cW = (const float*)d_in[6];
  const float* cb = (const float*)d_in[7];
  const float* wih = (const float*)d_in[8];
  const float* whh = (const float*)d_in[9];
  const float* bih = (const float*)d_in[10];
  const float* bhh = (const float*)d_in[11];
  const float* oW = (const float*)d_in[12];
  const float* ob = (const float*)d_in[13];
  const float* cs = (const float*)d_in[14];
  const float* ce = (const float*)d_in[15];
  const float* ct = (const float*)d_in[16];
  float* ws = (float*)d_ws;
  float* out = (float*)d_out;

  kPrep<<<dim3(8192), dim3(256), 0, stream>>>(wih, whh, aW, oW, cW, ct, ws);
  kInit<<<dim3(256), dim3(256), 0, stream>>>(dec, tags, emb, cs, ce, ct, ws);
  kEncW<<<dim3(2048), dim3(256), 0, stream>>>(enc, cW, (u16*)d_ws);

  P9 p;
  p.dec = dec; p.tags = tags; p.emb = emb;
  p.ab = ab; p.cb = cb; p.bih = bih; p.bhh = bhh;
  p.ob = ob; p.cs = cs; p.ws = ws;
  void* args[] = { &p };
  hipLaunchCooperativeKernel((void*)maink, dim3(256), dim3(512), args, 0, stream);

  kFinal<<<dim3(1), dim3(128), 0, stream>>>(ws, ce, out);
}

// Round 11
// 7625.034 us; speedup vs baseline: 1.5814x; 1.0995x over previous
//
#include <hip/hip_runtime.h>

// Round 11: R10 structure + (a) encT stored as custom fp8 (FTZ e4m3) halving
// the per-step stream bytes, (b) kEncW rewritten as bf16-MFMA GEMM (one block
// per t, LDS-staged enc chunks). cWh bf16 lives in the 16MB freed by fp8 encT.
// Phases/barrier/guards identical to R10 (absmax 0 lineage).

typedef unsigned short u16;
typedef unsigned int u32;
typedef __attribute__((ext_vector_type(8))) short short8;
typedef __attribute__((ext_vector_type(4))) float f32x4;
typedef __attribute__((ext_vector_type(4))) u32 u32x4;
typedef __attribute__((ext_vector_type(2))) u32 u32x2;

#define MFMA16(a, b, c) __builtin_amdgcn_mfma_f32_16x16x32_bf16((a), (b), (c), 0, 0, 0)

// ---- ws layout ----
// bytes [0, 16MB): encF fp8 [128 b][256 t][512 c]
// bytes [16MB, 17MB): cWh bf16 [512][1024]
#define U_CWH 8388608u     // u16 offset of cWh
#define U_WHH 16777216u    // [1536][512]
#define U_WIH 17563648u    // [1536][512]
#define U_WAW 18350080u    // [256][768]
#define U_WOW 18546688u    // [256][512]
#define U_WCE 18677760u    // [512][256]
#define U_WXT 18808832u    // [256][256]
#define U_HB  18874368u    // h bf16 [128][512]
#define U_EB  18939904u    // e bf16 [128][256]
#define U_XB  18972672u    // x bf16 [128][512]
#define U_PB  19038208u    // p bf16 [128][256]
#define F_LGB 9535488u
#define F_EMB 9568256u
#define F_EPB 9601024u
#define F_GHB 9666560u
#define F_SRB 9863168u
#define F_MFB 9895936u
#define F_NEB 9896064u
#define F_NSB 9896192u
#define F_BAR 9896448u     // u32: L1[771][16]x16 (197376) + REL[771]
#define BAR_N 198147u

__device__ __forceinline__ float bf2f(u16 u) { return __uint_as_float(((u32)u) << 16); }
__device__ __forceinline__ u16 f2bf(float f) {
  u32 u = __float_as_uint(f);
  return (u16)((u + 0x7FFFu + ((u >> 16) & 1u)) >> 16);
}
__device__ __forceinline__ u32 pk2(float a, float b) {
  return (u32)f2bf(a) | ((u32)f2bf(b) << 16);
}

// ---- custom fp8 (e4m3, FTZ, bias so decode = +120<<23) ----
__device__ __forceinline__ u32 enc8(float v) {
  const u32 b = __float_as_uint(v);
  const u32 sign = (b >> 24) & 0x80u;
  const int eb = (int)((b >> 23) & 0xFFu) - 120;
  if (eb <= 0) return sign;              // FTZ (|v| < 2^-6)
  const u32 m3 = ((b & 0x7FFFFFu) + 0x80000u) >> 20;  // rounded top-3 mant
  u32 val = ((u32)eb << 3) + m3;         // mant carry propagates into exp
  if (val > 0x7Fu) val = 0x7Fu;          // clamp to 480
  return sign | val;
}
__device__ __forceinline__ float dec8(u32 byte) {
  const u32 t = byte & 0x7Fu;
  u32 bits = (t << 20) + (120u << 23);
  bits |= (byte & 0x80u) << 24;
  const float f = __uint_as_float(bits);
  return (t & 0x78u) ? f : 0.f;
}

// ---- coherent (sc0 sc1) load/store helpers ----
__device__ __forceinline__ float ldcg_f(const float* p) {
  float r;
  asm volatile("global_load_dword %0, %1, off sc0 sc1\n\ts_waitcnt vmcnt(0)"
               : "=v"(r) : "v"(p));
  return r;
}
__device__ __forceinline__ f32x4 ldcg_f4(const float* p) {
  f32x4 r;
  asm volatile("global_load_dwordx4 %0, %1, off sc0 sc1\n\ts_waitcnt vmcnt(0)"
               : "=v"(r) : "v"(p));
  return r;
}
__device__ __forceinline__ u32x2 ldcg_b8(const u16* p) {
  u32x2 r;
  asm volatile("global_load_dwordx2 %0, %1, off sc0 sc1\n\ts_waitcnt vmcnt(0)"
               : "=v"(r) : "v"(p));
  return r;
}
__device__ __forceinline__ void ldcg_f4x3(f32x4& a, f32x4& b, f32x4& c,
                                          const float* p0, const float* p1,
                                          const float* p2) {
  asm volatile(
      "global_load_dwordx4 %0, %3, off sc0 sc1\n\t"
      "global_load_dwordx4 %1, %4, off sc0 sc1\n\t"
      "global_load_dwordx4 %2, %5, off sc0 sc1\n\t"
      "s_waitcnt vmcnt(0)"
      : "=&v"(a), "=&v"(b), "=&v"(c)
      : "v"(p0), "v"(p1), "v"(p2));
}
__device__ __forceinline__ void ldcg8(u32x4 d[8], const u16* p) {
  asm volatile(
      "global_load_dwordx4 %0, %8, off sc0 sc1\n\t"
      "global_load_dwordx4 %1, %8, off offset:64 sc0 sc1\n\t"
      "global_load_dwordx4 %2, %8, off offset:128 sc0 sc1\n\t"
      "global_load_dwordx4 %3, %8, off offset:192 sc0 sc1\n\t"
      "global_load_dwordx4 %4, %8, off offset:256 sc0 sc1\n\t"
      "global_load_dwordx4 %5, %8, off offset:320 sc0 sc1\n\t"
      "global_load_dwordx4 %6, %8, off offset:384 sc0 sc1\n\t"
      "global_load_dwordx4 %7, %8, off offset:448 sc0 sc1\n\t"
      "s_waitcnt vmcnt(0)"
      : "=&v"(d[0]), "=&v"(d[1]), "=&v"(d[2]), "=&v"(d[3]),
        "=&v"(d[4]), "=&v"(d[5]), "=&v"(d[6]), "=&v"(d[7])
      : "v"(p));
}
__device__ __forceinline__ void ldcg16(u32x4 d[16], const u16* p) {
  asm volatile(
      "global_load_dwordx4 %0, %16, off sc0 sc1\n\t"
      "global_load_dwordx4 %1, %16, off offset:64 sc0 sc1\n\t"
      "global_load_dwordx4 %2, %16, off offset:128 sc0 sc1\n\t"
      "global_load_dwordx4 %3, %16, off offset:192 sc0 sc1\n\t"
      "global_load_dwordx4 %4, %16, off offset:256 sc0 sc1\n\t"
      "global_load_dwordx4 %5, %16, off offset:320 sc0 sc1\n\t"
      "global_load_dwordx4 %6, %16, off offset:384 sc0 sc1\n\t"
      "global_load_dwordx4 %7, %16, off offset:448 sc0 sc1\n\t"
      "global_load_dwordx4 %8, %16, off offset:512 sc0 sc1\n\t"
      "global_load_dwordx4 %9, %16, off offset:576 sc0 sc1\n\t"
      "global_load_dwordx4 %10, %16, off offset:640 sc0 sc1\n\t"
      "global_load_dwordx4 %11, %16, off offset:704 sc0 sc1\n\t"
      "global_load_dwordx4 %12, %16, off offset:768 sc0 sc1\n\t"
      "global_load_dwordx4 %13, %16, off offset:832 sc0 sc1\n\t"
      "global_load_dwordx4 %14, %16, off offset:896 sc0 sc1\n\t"
      "global_load_dwordx4 %15, %16, off offset:960 sc0 sc1\n\t"
      "s_waitcnt vmcnt(0)"
      : "=&v"(d[0]), "=&v"(d[1]), "=&v"(d[2]), "=&v"(d[3]),
        "=&v"(d[4]), "=&v"(d[5]), "=&v"(d[6]), "=&v"(d[7]),
        "=&v"(d[8]), "=&v"(d[9]), "=&v"(d[10]), "=&v"(d[11]),
        "=&v"(d[12]), "=&v"(d[13]), "=&v"(d[14]), "=&v"(d[15])
      : "v"(p));
}
__device__ __forceinline__ void stcg_f(float* p, float v) {
  asm volatile("global_store_dword %0, %1, off sc0 sc1" ::"v"(p), "v"(v) : "memory");
}
__device__ __forceinline__ void stcg_f4(float* p, f32x4 v) {
  asm volatile("global_store_dwordx4 %0, %1, off sc0 sc1" ::"v"(p), "v"(v) : "memory");
}
__device__ __forceinline__ void stcg_b8(u16* p, u32x2 v) {
  asm volatile("global_store_dwordx2 %0, %1, off sc0 sc1" ::"v"(p), "v"(v) : "memory");
}

// ---- two-level generation-indexed grid barrier ----
__device__ __forceinline__ void gbar2(u32* bar, u32 gen, int grp) {
  __syncthreads();
  if (threadIdx.x == 0) {
    u32* l1 = bar + ((size_t)gen * 16u + (u32)grp) * 16u;
    u32* rel = bar + 197376u + gen;
    const u32 old = __hip_atomic_fetch_add(l1, 1u, __ATOMIC_RELAXED,
                                           __HIP_MEMORY_SCOPE_AGENT);
    if (old == 15u)
      __hip_atomic_fetch_add(rel, 1u, __ATOMIC_RELAXED, __HIP_MEMORY_SCOPE_AGENT);
    while (__hip_atomic_load(rel, __ATOMIC_RELAXED, __HIP_MEMORY_SCOPE_AGENT) < 16u) {}
  }
  __syncthreads();
}

// ---------------- weight convert (2,621,440 elems) ----------------
__global__ void __launch_bounds__(256) kPrep(const float* __restrict__ wih,
                                             const float* __restrict__ whh,
                                             const float* __restrict__ aW,
                                             const float* __restrict__ oW,
                                             const float* __restrict__ cW,
                                             const float* __restrict__ ct,
                                             float* __restrict__ ws) {
  u16* W = (u16*)ws;
  const u32 i = blockIdx.x * 256 + threadIdx.x;
  if (i < 786432u) {
    W[U_WHH + i] = f2bf(whh[i]);
  } else if (i < 1572864u) {
    const u32 j = i - 786432u;
    W[U_WIH + j] = f2bf(wih[j]);
  } else if (i < 1769472u) {
    const u32 j = i - 1572864u;
    W[U_WAW + j] = f2bf(aW[j]);
  } else if (i < 1900544u) {
    const u32 j = i - 1769472u;
    W[U_WOW + j] = f2bf(oW[j]);
  } else if (i < 2031616u) {
    const u32 j = i - 1900544u;
    W[U_WCE + j] = f2bf(cW[(size_t)(j >> 8) * 1280 + (j & 255u)]);
  } else if (i < 2097152u) {
    const u32 j = i - 2031616u;
    const u32 kn = j >> 8, k = j & 255u;
    W[U_WXT + j] = f2bf(__expf(ct[k * 256u + kn]));
  } else {
    const u32 j = i - 2097152u;  // cWh: [512 c][1024 j] = cW[c][256+j]
    const u32 c = j >> 10, jj = j & 1023u;
    W[U_CWH + j] = f2bf(cW[(size_t)c * 1280 + 256 + jj]);
  }
}

// ---------------- init ----------------
__global__ void __launch_bounds__(256) kInit(const int* __restrict__ dec,
                                             const int* __restrict__ tags,
                                             const float* __restrict__ emb,
                                             const float* __restrict__ cs,
                                             const float* __restrict__ ce,
                                             const float* __restrict__ ct,
                                             float* __restrict__ ws) {
  const u32 idx = blockIdx.x * 256 + threadIdx.x;  // 65536
  u16* W = (u16*)ws;
  u16* HB = W + U_HB;
  u16* EB = W + U_EB;
  if (idx < 32768u) {
    ((u32*)HB)[idx] = 0u;
    const int b = idx >> 8, j = idx & 255;
    EB[idx] = f2bf(emb[(size_t)dec[b] * 256 + j]);
  }
  if (idx < 128u) {
    int prev = tags[idx];
    float a = cs[prev];
    for (int t = 1; t < 256; ++t) {
      const int cur = tags[t * 128 + idx];
      a += ct[prev * 256 + cur];
      prev = cur;
    }
    ws[F_NSB + idx] = a + ce[prev];
    ws[F_NEB + idx] = 0.f;
  }
  u32* bar = (u32*)(ws + F_BAR);
  if (idx < 49537u) {
#pragma unroll
    for (int j = 0; j < 4; ++j) {
      const u32 k = idx * 4u + (u32)j;
      if (k < BAR_N) bar[k] = 0u;
    }
  }
}

// ---------------- encF[b][t][c] (fp8) = enc[t] @ cWh^T via MFMA ----------------
// one block per t; 8 waves; wave w owns c in [w*64, w*64+64)
__global__ void __launch_bounds__(512, 1) kEncW(const float* __restrict__ enc,
                                                const u16* __restrict__ cWh,
                                                unsigned char* __restrict__ encF) {
  __shared__ u16 ebuf[128][72];  // 72-stride: 144B rows (16B-aligned, low conflict)
  const int t = blockIdx.x;
  const int tid = threadIdx.x;
  const int w = tid >> 6, lane = tid & 63;
  const int bq = lane & 15, kg = lane >> 4;
  const int cw0 = w * 64;
  const float* encB = enc + (size_t)t * 131072;
  f32x4 acc[4][8];
#pragma unroll
  for (int ct = 0; ct < 4; ++ct)
#pragma unroll
    for (int bt = 0; bt < 8; ++bt) acc[ct][bt] = (f32x4){0.f, 0.f, 0.f, 0.f};
  for (int jc = 0; jc < 16; ++jc) {
    const int j0 = jc * 64;
    __syncthreads();
    {  // stage enc[t][:, j0..j0+63] -> bf16 LDS
      const int jp = tid & 31, bb = tid >> 5;  // jp: j-pair, bb: 0..15
#pragma unroll
      for (int pass = 0; pass < 8; ++pass) {
        const int b = pass * 16 + bb;
        const float2 v = *(const float2*)(encB + (size_t)b * 1024 + j0 + jp * 2);
        *(u32*)((char*)&ebuf[b][0] + jp * 4) = pk2(v.x, v.y);
      }
    }
    __syncthreads();
#pragma unroll
    for (int kk = 0; kk < 2; ++kk) {
      short8 Bf[8];
#pragma unroll
      for (int bt = 0; bt < 8; ++bt)
        Bf[bt] = *(const short8*)((const char*)&ebuf[bt * 16 + bq][0] +
                                  (kk * 32 + kg * 8) * 2);
#pragma unroll
      for (int ct = 0; ct < 4; ++ct) {
        const short8 Af = *(const short8*)(cWh +
            (size_t)(cw0 + ct * 16 + bq) * 1024 + j0 + kk * 32 + kg * 8);
#pragma unroll
        for (int bt = 0; bt < 8; ++bt)
          acc[ct][bt] = MFMA16(Af, Bf[bt], acc[ct][bt]);
      }
    }
  }
#pragma unroll
  for (int ct = 0; ct < 4; ++ct)
#pragma unroll
    for (int bt = 0; bt < 8; ++bt) {
      const int b = bt * 16 + bq;
      const int c0 = cw0 + ct * 16 + kg * 4;
      const u32 pk = enc8(acc[ct][bt][0]) | (enc8(acc[ct][bt][1]) << 8) |
                     (enc8(acc[ct][bt][2]) << 16) | (enc8(acc[ct][bt][3]) << 24);
      *(u32*)(encF + (size_t)b * 131072 + (size_t)t * 512 + c0) = pk;
    }
}

struct P9 {
  const int* dec; const int* tags; const float* emb;
  const float* ab; const float* cb; const float* bih; const float* bhh;
  const float* ob; const float* cs;
  float* ws;
};

// ---------------- main cooperative kernel ----------------
__global__ void __launch_bounds__(512, 2) maink(P9 p) {
  float* const ws = p.ws;
  u16* const W16 = (u16*)ws;
  const unsigned char* const ENCF = (const unsigned char*)ws;
  const u16* const WHH16 = W16 + U_WHH;
  const u16* const WIH16 = W16 + U_WIH;
  const u16* const WAW16 = W16 + U_WAW;
  const u16* const WOW16 = W16 + U_WOW;
  const u16* const WCE16 = W16 + U_WCE;
  const u16* const WXT16 = W16 + U_WXT;
  u16* const HB = W16 + U_HB;
  u16* const EB = W16 + U_EB;
  u16* const XB = W16 + U_XB;
  u16* const PBu = W16 + U_PB;
  float* const LGB = ws + F_LGB;
  float* const EMB = ws + F_EMB;
  float* const EPB = ws + F_EPB;
  float* const GHB = ws + F_GHB;
  float* const SRB = ws + F_SRB;
  float* const MFB = ws + F_MFB;
  float* const NEB = ws + F_NEB;
  u32* const bar = (u32*)(ws + F_BAR);

  __shared__ float prL[256];
  __shared__ float pacc[8][260];
  __shared__ float red[16];
  __shared__ float pr3[3][256];

  const int tid = threadIdx.x;
  const int w = tid >> 6, lane = tid & 63;
  const int bq = lane & 15, kg = lane >> 4;
  const int blk = blockIdx.x;
  const int grp = blk >> 4;
  u32 gen = 0;

  for (int s = 0; s <= 256; ++s) {
    // ================= P1 =================
    if (w < 3) {
      if (s < 256) {  // gh: t = w*256+blk
        const int t = w * 256 + blk;
        const int r0 = (t >> 3) * 16, b0 = (t & 7) * 16;
        f32x4 acc;
        const float4 bs = *(const float4*)(p.bhh + r0 + kg * 4);
        acc[0] = bs.x; acc[1] = bs.y; acc[2] = bs.z; acc[3] = bs.w;
        u32x4 Bf[16];
        ldcg16(Bf, HB + (size_t)(b0 + bq) * 512 + kg * 8);
        const u16* Ar = WHH16 + (size_t)(r0 + bq) * 512 + kg * 8;
#pragma unroll
        for (int kt = 0; kt < 16; ++kt)
          acc = MFMA16(*(const short8*)(Ar + kt * 32),
                       __builtin_bit_cast(short8, Bf[kt]), acc);
        stcg_f4(GHB + (size_t)(b0 + bq) * 1536 + r0 + kg * 4, acc);
      }
    } else if (w == 3) {
      if (blk < 128) {
        if (s < 256) {  // attn logits, K=768
          const int r0 = (blk >> 3) * 16, b0 = (blk & 7) * 16;
          f32x4 acc;
          const float4 bs = *(const float4*)(p.ab + r0 + kg * 4);
          acc[0] = bs.x; acc[1] = bs.y; acc[2] = bs.z; acc[3] = bs.w;
          u32x4 Ef[8], Hf[16];
          ldcg8(Ef, EB + (size_t)(b0 + bq) * 256 + kg * 8);
          ldcg16(Hf, HB + (size_t)(b0 + bq) * 512 + kg * 8);
          const u16* Ar = WAW16 + (size_t)(r0 + bq) * 768 + kg * 8;
#pragma unroll
          for (int kt = 0; kt < 8; ++kt)
            acc = MFMA16(*(const short8*)(Ar + kt * 32),
                         __builtin_bit_cast(short8, Ef[kt]), acc);
#pragma unroll
          for (int kt = 0; kt < 16; ++kt)
            acc = MFMA16(*(const short8*)(Ar + 256 + kt * 32),
                         __builtin_bit_cast(short8, Hf[kt]), acc);
          stcg_f4(LGB + (size_t)(b0 + bq) * 256 + r0 + kg * 4, acc);
        }
      } else {
        if (s >= 1) {  // em_{s-1} from current h
          const int t2 = blk - 128;
          const int r0 = (t2 >> 3) * 16, b0 = (t2 & 7) * 16;
          f32x4 acc;
          const float4 bs = *(const float4*)(p.ob + r0 + kg * 4);
          acc[0] = bs.x; acc[1] = bs.y; acc[2] = bs.z; acc[3] = bs.w;
          u32x4 Hf[16];
          ldcg16(Hf, HB + (size_t)(b0 + bq) * 512 + kg * 8);
          const u16* Ar = WOW16 + (size_t)(r0 + bq) * 512 + kg * 8;
#pragma unroll
          for (int kt = 0; kt < 16; ++kt)
            acc = MFMA16(*(const short8*)(Ar + kt * 32),
                         __builtin_bit_cast(short8, Hf[kt]), acc);
          stcg_f4(EMB + (size_t)(b0 + bq) * 256 + r0 + kg * 4, acc);
        }
      }
    } else if (w == 4) {
      if (s < 256) {  // ep = cb + cWe @ e
        const int r0 = (blk >> 3) * 16, b0 = (blk & 7) * 16;
        f32x4 acc;
        const float4 bs = *(const float4*)(p.cb + r0 + kg * 4);
        acc[0] = bs.x; acc[1] = bs.y; acc[2] = bs.z; acc[3] = bs.w;
        u32x4 Ef[8];
        ldcg8(Ef, EB + (size_t)(b0 + bq) * 256 + kg * 8);
        const u16* Ar = WCE16 + (size_t)(r0 + bq) * 256 + kg * 8;
#pragma unroll
        for (int kt = 0; kt < 8; ++kt)
          acc = MFMA16(*(const short8*)(Ar + kt * 32),
                       __builtin_bit_cast(short8, Ef[kt]), acc);
        stcg_f4(EPB + (size_t)(b0 + bq) * 512 + r0 + kg * 4, acc);
      }
    } else if (w == 5) {
      if (blk < 128 && s >= 2) {  // CRF-A
        const int b = blk;
        const f32x4 sv = ldcg_f4(SRB + (size_t)b * 256 + lane * 4);
        float mx = fmaxf(fmaxf(sv[0], sv[1]), fmaxf(sv[2], sv[3]));
#pragma unroll
        for (int o = 32; o; o >>= 1) mx = fmaxf(mx, __shfl_xor(mx, o));
        u32x2 pv;
        pv[0] = pk2(__expf(sv[0] - mx), __expf(sv[1] - mx));
        pv[1] = pk2(__expf(sv[2] - mx), __expf(sv[3] - mx));
        stcg_b8(PBu + (size_t)b * 256 + lane * 4, pv);
        if (lane == 0) stcg_f(MFB + b, mx);
      }
    }
    gbar2(bar, gen++, grp);

    // ================= P2 (b = blk&127, c-half = blk>>7) =================
    {
      const int b = blk & 127, chalf = blk >> 7;
      if (s < 256) {
        float v = -3.0e38f;
        if (tid < 256) v = ldcg_f(LGB + (size_t)b * 256 + tid);
        float m = v;
#pragma unroll
        for (int o = 32; o; o >>= 1) m = fmaxf(m, __shfl_xor(m, o));
        if (lane == 0) red[w] = m;
        __syncthreads();
        float mB = red[0];
#pragma unroll
        for (int q = 1; q < 8; ++q) mB = fmaxf(mB, red[q]);
        float e = 0.f;
        if (tid < 256) { e = __expf(v - mB); prL[tid] = e; }
        float sacc = e;
#pragma unroll
        for (int o = 32; o; o >>= 1) sacc += __shfl_xor(sacc, o);
        if (lane == 0) red[8 + w] = sacc;
        __syncthreads();
        float sum = red[8];
#pragma unroll
        for (int q = 1; q < 8; ++q) sum += red[8 + q];
        const float inv = 1.f / sum;
        // fp8 stream: wave w owns t in [w*32, w*32+32), lane owns a c-quad
        const unsigned char* basef = ENCF + (size_t)b * 131072u +
                                     (size_t)(w * 32) * 512u +
                                     (chalf * 256 + lane * 4);
        const float* prh = prL + w * 32;
        float a0 = 0.f, a1 = 0.f, a2 = 0.f, a3 = 0.f;
#pragma unroll 8
        for (int t = 0; t < 32; ++t) {
          const float prt = prh[t];
          const u32 vv = *(const u32*)(basef + (size_t)t * 512);
          a0 = fmaf(prt, dec8(vv & 0xFFu), a0);
          a1 = fmaf(prt, dec8((vv >> 8) & 0xFFu), a1);
          a2 = fmaf(prt, dec8((vv >> 16) & 0xFFu), a2);
          a3 = fmaf(prt, dec8(vv >> 24), a3);
        }
        float* pw = &pacc[w][lane * 4];
        pw[0] = a0; pw[1] = a1; pw[2] = a2; pw[3] = a3;
        __syncthreads();
        if (tid < 64) {
          const int cl = tid * 4;
          f32x4 s8 = (f32x4){0.f, 0.f, 0.f, 0.f};
#pragma unroll
          for (int g = 0; g < 8; ++g) {
            s8[0] += pacc[g][cl];
            s8[1] += pacc[g][cl + 1];
            s8[2] += pacc[g][cl + 2];
            s8[3] += pacc[g][cl + 3];
          }
          const f32x4 ep4 = ldcg_f4(EPB + (size_t)b * 512 + chalf * 256 + cl);
          float xv[4];
#pragma unroll
          for (int r = 0; r < 4; ++r)
            xv[r] = fmaxf(ep4[r] + s8[r] * inv, 0.f);
          u32x2 xo;
          xo[0] = pk2(xv[0], xv[1]);
          xo[1] = pk2(xv[2], xv[3]);
          stcg_b8(XB + (size_t)b * 512 + chalf * 256 + cl, xo);
        }
      }
      if (chalf == 0 && s >= 1 && tid == 0) {
        const int tg = p.tags[(s - 1) * 128 + b];
        const float em = ldcg_f(EMB + (size_t)b * 256 + tg);
        const float ne = ldcg_f(NEB + b);
        stcg_f(NEB + b, ne + em);
      }
    }
    gbar2(bar, gen++, grp);

    // ================= P3 =================
    f32x4 R, Z, N;
    const bool giact = (s < 256) && (w == 0 || w == 2);
    if (giact) {
      const int r0 = (blk >> 3) * 16, b0 = (blk & 7) * 16;
      const int kh = w >> 1;
      if (kh == 0) {
        const float4 b1 = *(const float4*)(p.bih + r0 + kg * 4);
        const float4 b2 = *(const float4*)(p.bih + 512 + r0 + kg * 4);
        const float4 b3 = *(const float4*)(p.bih + 1024 + r0 + kg * 4);
        R[0] = b1.x; R[1] = b1.y; R[2] = b1.z; R[3] = b1.w;
        Z[0] = b2.x; Z[1] = b2.y; Z[2] = b2.z; Z[3] = b2.w;
        N[0] = b3.x; N[1] = b3.y; N[2] = b3.z; N[3] = b3.w;
      } else {
        R = (f32x4){0.f, 0.f, 0.f, 0.f}; Z = R; N = R;
      }
      u32x4 Xf[8];
      ldcg8(Xf, XB + (size_t)(b0 + bq) * 512 + kh * 256 + kg * 8);
      const u16* ArR = WIH16 + (size_t)(r0 + bq) * 512 + kh * 256 + kg * 8;
      const u16* ArZ = ArR + (size_t)512 * 512;
      const u16* ArN = ArR + (size_t)1024 * 512;
#pragma unroll
      for (int kt = 0; kt < 8; ++kt) {
        const short8 bb = __builtin_bit_cast(short8, Xf[kt]);
        R = MFMA16(*(const short8*)(ArR + kt * 32), bb, R);
        Z = MFMA16(*(const short8*)(ArZ + kt * 32), bb, Z);
        N = MFMA16(*(const short8*)(ArN + kt * 32), bb, N);
      }
      if (w == 2) {
#pragma unroll
        for (int r = 0; r < 4; ++r) {
          pr3[0][(kg * 4 + r) * 16 + bq] = R[r];
          pr3[1][(kg * 4 + r) * 16 + bq] = Z[r];
          pr3[2][(kg * 4 + r) * 16 + bq] = N[r];
        }
      }
    }
    __syncthreads();
    if (s < 256 && w == 0) {  // combine + gates + h_new
      const int r0 = (blk >> 3) * 16, b0 = (blk & 7) * 16;
      const int b = b0 + bq;
      f32x4 gr4, gz4, gn4;
      ldcg_f4x3(gr4, gz4, gn4,
                GHB + (size_t)b * 1536 + r0 + kg * 4,
                GHB + (size_t)b * 1536 + 512 + r0 + kg * 4,
                GHB + (size_t)b * 1536 + 1024 + r0 + kg * 4);
      const u32x2 h4 = ldcg_b8(HB + (size_t)b * 512 + r0 + kg * 4);
      const float hold[4] = {bf2f((u16)(h4[0] & 0xffffu)), bf2f((u16)(h4[0] >> 16)),
                             bf2f((u16)(h4[1] & 0xffffu)), bf2f((u16)(h4[1] >> 16))};
      float hn[4];
#pragma unroll
      for (int r = 0; r < 4; ++r) {
        const float Rv = R[r] + pr3[0][(kg * 4 + r) * 16 + bq];
        const float Zv = Z[r] + pr3[1][(kg * 4 + r) * 16 + bq];
        const float Nv = N[r] + pr3[2][(kg * 4 + r) * 16 + bq];
        const float rr = 1.f / (1.f + __expf(-(Rv + gr4[r])));
        const float zz = 1.f / (1.f + __expf(-(Zv + gz4[r])));
        const float nn = tanhf(Nv + rr * gn4[r]);
        hn[r] = (1.f - zz) * nn + zz * hold[r];
      }
      u32x2 ho;
      ho[0] = pk2(hn[0], hn[1]);
      ho[1] = pk2(hn[2], hn[3]);
      stcg_b8(HB + (size_t)b * 512 + r0 + kg * 4, ho);
    }
    if (w == 1) {
      if (blk < 128) {
        if (s >= 1) {  // CRF-B
          const int kn0 = (blk >> 3) * 16, b0 = (blk & 7) * 16;
          const int b = b0 + bq;
          if (s == 1) {
            const f32x4 e4 = ldcg_f4(EMB + (size_t)b * 256 + kn0 + kg * 4);
            const float4 c4 = *(const float4*)(p.cs + kn0 + kg * 4);
            f32x4 o;
            o[0] = c4.x + e4[0]; o[1] = c4.y + e4[1];
            o[2] = c4.z + e4[2]; o[3] = c4.w + e4[3];
            stcg_f4(SRB + (size_t)b * 256 + kn0 + kg * 4, o);
          } else {
            f32x4 acc = (f32x4){0.f, 0.f, 0.f, 0.f};
            u32x4 Pf[8];
            ldcg8(Pf, PBu + (size_t)(b0 + bq) * 256 + kg * 8);
            const u16* Ar = WXT16 + (size_t)(kn0 + bq) * 256 + kg * 8;
#pragma unroll
            for (int kt = 0; kt < 8; ++kt)
              acc = MFMA16(*(const short8*)(Ar + kt * 32),
                           __builtin_bit_cast(short8, Pf[kt]), acc);
            const float mf = ldcg_f(MFB + b);
            const f32x4 e4 = ldcg_f4(EMB + (size_t)b * 256 + kn0 + kg * 4);
            f32x4 o;
            o[0] = mf + __logf(acc[0]) + e4[0];
            o[1] = mf + __logf(acc[1]) + e4[1];
            o[2] = mf + __logf(acc[2]) + e4[2];
            o[3] = mf + __logf(acc[3]) + e4[3];
            stcg_f4(SRB + (size_t)b * 256 + kn0 + kg * 4, o);
          }
        }
      } else {
        if (s < 255) {  // stage e_{s+1}
          const int b = blk - 128;
          const int tok = p.tags[s * 128 + b];
          const float4 ev = *(const float4*)(p.emb + (size_t)tok * 256 + lane * 4);
          u32x2 ee;
          ee[0] = pk2(ev.x, ev.y);
          ee[1] = pk2(ev.z, ev.w);
          stcg_b8(EB + (size_t)b * 256 + lane * 4, ee);
        }
      }
    }
    gbar2(bar, gen++, grp);
  }
}

// ---------------- final: denominator + mean ----------------
__global__ void __launch_bounds__(128) kFinal(const float* __restrict__ ws,
                                              const float* __restrict__ ce,
                                              float* __restrict__ out) {
  __shared__ float acc[128];
  const int tid = threadIdx.x;
  const float* SRB = ws + F_SRB;
  float mx = -3.0e38f;
#pragma unroll 8
  for (int k = 0; k < 256; ++k) mx = fmaxf(mx, SRB[(size_t)tid * 256 + k] + ce[k]);
  float sm = 0.f;
#pragma unroll 8
  for (int k = 0; k < 256; ++k) sm += __expf(SRB[(size_t)tid * 256 + k] + ce[k] - mx);
  acc[tid] = ws[F_NSB + tid] + ws[F_NEB + tid] - (mx + __logf(sm));
  __syncthreads();
  if (tid < 64) {
    float v = acc[tid] + acc[tid + 64];
#pragma unroll
    for (int o = 32; o; o >>= 1) v += __shfl_xor(v, o);
    if (tid == 0) out[0] = v * (1.f / 128.f);
  }
}

extern "C" void kernel_launch(void* const* d_in, const int* in_sizes, int n_in,
                              void* d_out, int out_size, void* d_ws, size_t ws_size,
                              hipStream_t stream) {
  (void)in_sizes; (void)n_in; (void)out_size; (void)ws_size;
  const int* dec = (const int*)d_in[0];
  const int* tags = (const int*)d_in[1];
  const float* enc = (const float*)d_in[2];
  const float* emb = (const float*)d_in[3];
  const float* aW = (const float*)d_in[4];
  const float* ab = (const float*)d_in[5];
  const float* cW = (const float*)d_in[6];
  const float* cb = (const float*)d_in[7];
  const float* wih = (const float*)d_in[8];
  const float* whh = (const float*)d_in[9];
  const float* bih = (const float*)d_in[10];
  const float* bhh = (const float*)d_in[11];
  const float* oW = (const float*)d_in[12];
  const float* ob = (const float*)d_in[13];
  const float* cs = (const float*)d_in[14];
  const float* ce = (const float*)d_in[15];
  const float* ct = (const float*)d_in[16];
  float* ws = (float*)d_ws;
  float* out = (float*)d_out;

  kPrep<<<dim3(10240), dim3(256), 0, stream>>>(wih, whh, aW, oW, cW, ct, ws);
  kInit<<<dim3(256), dim3(256), 0, stream>>>(dec, tags, emb, cs, ce, ct, ws);
  kEncW<<<dim3(256), dim3(512), 0, stream>>>(enc, (const u16*)ws + U_CWH,
                                             (unsigned char*)d_ws);

  P9 p;
  p.dec = dec; p.tags = tags; p.emb = emb;
  p.ab = ab; p.cb = cb; p.bih = bih; p.bhh = bhh;
  p.ob = ob; p.cs = cs; p.ws = ws;
  void* args[] = { &p };
  hipLaunchCooperativeKernel((void*)maink, dim3(256), dim3(512), args, 0, stream);

  kFinal<<<dim3(1), dim3(128), 0, stream>>>(ws, ce, out);
}